// Round 6
// baseline (39102.533 us; speedup 1.0000x reference)
//
#include <hip/hip_runtime.h>
#include <stdint.h>

// Problem sizes
#define Bz 32
#define Tz 512
#define Ez 768
#define Hz 512
#define G4 2048      // 4*H
#define AK 768       // staged A-matrix: ctx cols only (x read direct, h in parity bufs)
#define NBLK 256
#define NSTEP 512

typedef __attribute__((ext_vector_type(8))) short short8;
typedef __attribute__((ext_vector_type(4))) float f32x4;

// ---------------- ws layout (bytes) — total identical to proven 77881344 ----------------
#define OFF_SUB    0u            // 32 sub-barrier counters, 64B padded
#define OFF_GRP    2048u         // 32 group counters, 64B padded
#define OFF_AMATH  4096u         // 64*768 bf16 = 98304 (ctx only)
#define OFF_AMATL  102400u       // 98304 -> ends 200704
#define OFF_FLAGS  200704u       // 32 release-flag lines = 2048 -> ends 202752
#define OFF_TOP    202752u       // top counter, own line (slack to 397312)
#define OFF_HPH    397312u       // 2par*2dir*32*512 bf16 hi = 131072
#define OFF_HPL    528384u       // 131072
#define CTRL_BYTES 659456u       // memset-0: sub/grp/amat/flags/top/hp
#define OFF_DEC    659456u       // 2*32*512 f32 = 131072 (write-before-read)
#define OFF_PSTAT  790528u       // 2*32*8*2 f32 = 4096
#define OFF_BIASG  794624u       // 2*2048 f32 = 16384
#define OFF_PCTX   811008u       // 2*32*8*768 f32 = 1572864
#define OFF_EMB16  2383872u      // 32*512*768 bf16 = 25165824
#define OFF_EP32   27549696u     // 32*512*512 f32 = 33554432
#define OFF_WIH    61104128u     // 2*2048*1536 bf16 = 12582912
#define OFF_WHH    73687040u     // 2*2048*512 bf16 = 4194304
// wenc hi/lo alias the scan-only pctx region (encgemm finishes before scan writes pctx)
#define OFF_WENCHI OFF_PCTX
#define OFF_WENCLO (OFF_PCTX + 786432u)
#define WS_NEEDED  77881344u     // == proven footprint of the passing kernel

__device__ __forceinline__ float b2f(short s){
  union { unsigned int u; float f; } w;
  w.u = ((unsigned int)(unsigned short)s) << 16;
  return w.f;
}
__device__ __forceinline__ unsigned short f2b(float f){
  union { float f; unsigned int u; } w; w.f = f;
  unsigned int u = w.u;
  return (unsigned short)((u + 0x7fffu + ((u >> 16) & 1u)) >> 16);
}
__device__ __forceinline__ unsigned int pk(float x){
  const unsigned short h = f2b(x);
  const unsigned short l = f2b(x - b2f((short)h));
  return ((unsigned int)h << 16) | (unsigned int)l;
}
__device__ __forceinline__ float fast_tanh(float x){
  float e = __expf(2.f * x);
  return 1.f - 2.f / (e + 1.f);
}
__device__ __forceinline__ float sigf(float x){
  return 1.f / (1.f + __expf(-x));
}
__device__ __forceinline__ float wsum(float v){
  #pragma unroll
  for (int o = 32; o > 0; o >>= 1) v += __shfl_xor(v, o, 64);
  return v;
}
__device__ __forceinline__ float wmaxr(float v){
  #pragma unroll
  for (int o = 32; o > 0; o >>= 1) v = fmaxf(v, __shfl_xor(v, o, 64));
  return v;
}

// relaxed agent-scope atomic access (sc-flagged; bypasses non-coherent L2)
__device__ __forceinline__ unsigned int ald32(const unsigned int* p){
  return __hip_atomic_load(p, __ATOMIC_RELAXED, __HIP_MEMORY_SCOPE_AGENT);
}
__device__ __forceinline__ float ald32f(const float* p){
  return __hip_atomic_load(p, __ATOMIC_RELAXED, __HIP_MEMORY_SCOPE_AGENT);
}
__device__ __forceinline__ unsigned long long ald64(const unsigned long long* p){
  return __hip_atomic_load(p, __ATOMIC_RELAXED, __HIP_MEMORY_SCOPE_AGENT);
}
__device__ __forceinline__ void ast32(unsigned int* p, unsigned int v){
  __hip_atomic_store(p, v, __ATOMIC_RELAXED, __HIP_MEMORY_SCOPE_AGENT);
}
__device__ __forceinline__ void ast32f(float* p, float v){
  __hip_atomic_store(p, v, __ATOMIC_RELAXED, __HIP_MEMORY_SCOPE_AGENT);
}
__device__ __forceinline__ short8 ald8s(const unsigned short* p){
  union { unsigned long long u[2]; short8 s; } w;
  const unsigned long long* q = (const unsigned long long*)p;
  w.u[0] = ald64(q);
  w.u[1] = ald64(q + 1);
  return w.s;
}

// Grid barrier, split arrive/wait. Arrival: 32 sub-counters (8 blocks each)
// -> top counter -> release written to 32 SEPARATE flag lines (pollers never
// share a line with arrival RMWs). Window work can be placed between arrive
// and wait. Fence-free: __syncthreads drains vmcnt per wave before s_barrier.
__device__ __forceinline__ void gbar_arrive(unsigned int* sub, unsigned int* top,
                                            unsigned int* flags, unsigned int bk,
                                            int blk, int tid){
  if (tid == 0){
    const unsigned int o =
        __hip_atomic_fetch_add(sub + (unsigned)(blk >> 3) * 16u, 1u,
                               __ATOMIC_RELAXED, __HIP_MEMORY_SCOPE_AGENT);
    if (o == 8u * bk - 1u){
      const unsigned int t =
          __hip_atomic_fetch_add(top, 1u, __ATOMIC_RELAXED,
                                 __HIP_MEMORY_SCOPE_AGENT);
      if (t == 32u * bk - 1u){
        #pragma unroll
        for (int i = 0; i < 32; ++i)
          __hip_atomic_store(flags + i * 16, bk, __ATOMIC_RELAXED,
                             __HIP_MEMORY_SCOPE_AGENT);
      }
    }
  }
}
__device__ __forceinline__ void gbar_wait(unsigned int* flags, unsigned int bk,
                                          int blk, int tid){
  if (tid == 0){
    while (__hip_atomic_load(flags + (unsigned)(blk >> 3) * 16u,
                             __ATOMIC_RELAXED, __HIP_MEMORY_SCOPE_AGENT) < bk)
      __builtin_amdgcn_s_sleep(2);
  }
  __syncthreads();
}

// 8-block batch-group sync (cumulative counter, target 8*gk)
__device__ __forceinline__ void gsync(unsigned int* grp, int b,
                                      unsigned int gk, int tid){
  __syncthreads();
  if (tid == 0){
    __hip_atomic_fetch_add(grp + (unsigned)b * 16u, 1u,
                           __ATOMIC_RELAXED, __HIP_MEMORY_SCOPE_AGENT);
    while (__hip_atomic_load(grp + (unsigned)b * 16u, __ATOMIC_RELAXED,
                             __HIP_MEMORY_SCOPE_AGENT) < 8u * gk)
      __builtin_amdgcn_s_sleep(1);
  }
  __syncthreads();
}

// ---------------- fp32 -> bf16 convert ----------------
__global__ void cvtk(const float* __restrict__ src, unsigned short* __restrict__ dst, int n){
  int i = blockIdx.x * blockDim.x + threadIdx.x;
  const int stride = gridDim.x * blockDim.x;
  for (; i < n; i += stride) dst[i] = f2b(src[i]);
}

// fp32 -> (hi, lo) bf16 Dekker split
__global__ void splitk(const float* __restrict__ src, unsigned short* __restrict__ hi,
                       unsigned short* __restrict__ lo, int n){
  int i = blockIdx.x * blockDim.x + threadIdx.x;
  const int stride = gridDim.x * blockDim.x;
  for (; i < n; i += stride){
    const float x = src[i];
    const unsigned short h = f2b(x);
    hi[i] = h;
    lo[i] = f2b(x - b2f((short)h));
  }
}

// bias_g[dir][j] = bih[j] + bhh[j]
__global__ void biask(const float* bihf, const float* bhhf,
                      const float* bihb, const float* bhhb, float* bg){
  int i = blockIdx.x * blockDim.x + threadIdx.x;
  if (i < G4) bg[i] = bihf[i] + bhhf[i];
  else if (i < 2 * G4) bg[i] = bihb[i - G4] + bhhb[i - G4];
}

// out[b][t][c] = bias_c (exclusive-owner accumulates happen in the scan)
__global__ void outinit(float* out, const float* parab, const float* chapb){
  const int i = blockIdx.x * blockDim.x + threadIdx.x;
  if (i < Bz * Tz * 8){
    const int c = i & 7;
    out[i] = (c < 5) ? parab[c] : chapb[c - 5];
  }
}

// ---------------- enc_proj GEMM (split-bf16, fp32-accurate) ----------------
__global__ __launch_bounds__(256, 1) void encgemm(
    const float* __restrict__ embf,
    const unsigned short* __restrict__ wenchi, const unsigned short* __restrict__ wenclo,
    const float* __restrict__ encb, float* __restrict__ ep32)
{
  const int lane = threadIdx.x & 63, wvv = threadIdx.x >> 6;
  const int mt = blockIdx.x * 4 + wvv;
  const int m0 = mt * 16;
  const int n = lane & 15, quad = lane >> 4;
  f32x4 acc[32];
  #pragma unroll
  for (int i = 0; i < 32; ++i) acc[i] = (f32x4){0.f, 0.f, 0.f, 0.f};
  const float* ar = embf + ((size_t)(m0 + n)) * Ez;
  for (int kk = 0; kk < 24; ++kk){
    const int k = kk * 32 + quad * 8;
    const f32x4 a0 = *(const f32x4*)(ar + k);
    const f32x4 a1 = *(const f32x4*)(ar + k + 4);
    short8 ah, al;
    #pragma unroll
    for (int j = 0; j < 4; ++j){
      unsigned short h0 = f2b(a0[j]);
      ah[j] = (short)h0; al[j] = (short)f2b(a0[j] - b2f((short)h0));
      unsigned short h1 = f2b(a1[j]);
      ah[4 + j] = (short)h1; al[4 + j] = (short)f2b(a1[j] - b2f((short)h1));
    }
    #pragma unroll
    for (int nt = 0; nt < 32; ++nt){
      const size_t bo = ((size_t)(nt * 16 + n)) * Ez + k;
      const short8 bh = *(const short8*)(wenchi + bo);
      const short8 bl = *(const short8*)(wenclo + bo);
      acc[nt] = __builtin_amdgcn_mfma_f32_16x16x32_bf16(ah, bh, acc[nt], 0, 0, 0);
      acc[nt] = __builtin_amdgcn_mfma_f32_16x16x32_bf16(ah, bl, acc[nt], 0, 0, 0);
      acc[nt] = __builtin_amdgcn_mfma_f32_16x16x32_bf16(al, bh, acc[nt], 0, 0, 0);
    }
  }
  #pragma unroll
  for (int nt = 0; nt < 32; ++nt){
    const int colg = nt * 16 + n;
    const float bb = encb[colg];
    #pragma unroll
    for (int r = 0; r < 4; ++r){
      const int row = m0 + quad * 4 + r;
      ep32[(size_t)row * Hz + colg] = acc[nt][r] + bb;
    }
  }
}

// ---------------- persistent scan kernel ----------------
// Per step: prefetch D's x/h operands into registers (their inputs are stable
// all through B) -> Phase B (h-stage, dec GEMV w/ register-pinned dec_W,
// split gsync #1 hiding the out-projection, scores, stats, ctx partials
// [u32 loads], gsync #2, fac, combine) -> gbar#1 split {arrive, zero gateval,
// wait} -> Phase D (gates MFMA: ctx from amat, x/h from prefetched regs,
// pointwise LSTM, h handoff) -> gbar#2.
__global__ __launch_bounds__(1024) void scan_kernel(
    unsigned int* sub, unsigned int* top, unsigned int* flags, unsigned int* grp,
    unsigned short* amathi, unsigned short* amatlo,
    unsigned short* hph, unsigned short* hpl,
    float* decw, float* pctx, float* pstat,
    const float* __restrict__ biasg,
    const float* __restrict__ embf, const unsigned short* __restrict__ emb16,
    const float* __restrict__ ep32,
    const unsigned short* __restrict__ wih16, const unsigned short* __restrict__ whh16,
    const float* __restrict__ decWf, const float* __restrict__ decbias,
    const float* __restrict__ vvec,
    const float* __restrict__ paraW, const float* __restrict__ chapW,
    float* __restrict__ out)
{
  __shared__ float eps_lds[64 * 512];   // 128 KB enc_proj slice, resident all steps
  __shared__ float hs[1024];            // staged h (both dirs, this batch)
  __shared__ float red[2112];           // dec partial reduce (16 k-chunks x 2dir x 64, padded)
  __shared__ float decs[1024];          // dec for this block's batch, both dirs
  __shared__ float scs[2][64];
  __shared__ float pw[2][64];
  __shared__ float fac[2][8];
  __shared__ float gateval[512];        // 16 batches x 32 col-units

  const int blk = blockIdx.x;
  const int tid = threadIdx.x;
  const int lane = tid & 63, wv = tid >> 6;

  const int d_dir = blk >> 7, mhalf = (blk >> 6) & 1, s4d = blk & 63;  // phase-D role
  const int b_b = blk >> 3, b_q = blk & 7;        // phase-B role (batch, t-slice)
  const int t0 = b_q * 64;

  // ---- preload ep slice into LDS (resident for all 512 steps) ----
  for (int i = tid; i < 8192; i += 1024){
    const int row = i >> 7;
    const int c4 = (i & 127) << 2;
    *(f32x4*)&eps_lds[row * 512 + c4] =
        *(const f32x4*)(ep32 + ((size_t)(b_b * Tz + t0 + row)) * Hz + c4);
  }
  // v in stride-64 lane layout (conflict-free score loop)
  float vr[8];
  #pragma unroll
  for (int j = 0; j < 8; ++j) vr[j] = vvec[j * 64 + lane];

  // ---- pin phase-D B-weight fragments in registers (same 256B every step) ----
  const int dn = lane & 15, dquad = lane >> 4;
  short8 Bfrag[4][2];
  #pragma unroll
  for (int kk = 0; kk < 4; ++kk){
    const int k = wv * 128 + kk * 32 + dquad * 8;
    #pragma unroll
    for (int j = 0; j < 2; ++j){
      const int coln = ((dn >> 2) * 512) + s4d * 8 + j * 4 + (dn & 3);
      Bfrag[kk][j] = (k < 1536)
        ? *(const short8*)(wih16 + ((size_t)(d_dir * G4) + coln) * 1536 + k)
        : *(const short8*)(whh16 + ((size_t)(d_dir * G4) + coln) * 512 + (k - 1536));
    }
  }
  // ---- pin dec_W slice in registers: thread (j2 = tid>>4, kc = tid&15)
  // covers row (b_q*64+j2), k in {kc, kc+16, ..., kc+496} ----
  float wreg[32];
  {
    const float* wrow = decWf + ((size_t)(b_q * 64 + (tid >> 4))) * Hz + (tid & 15);
    #pragma unroll
    for (int i = 0; i < 32; ++i) wreg[i] = wrow[i * 16];
  }
  float db_r = 0.f;
  if (tid < 128) db_r = decbias[b_q * 64 + (tid & 63)];

  // ---- pin out-projection weights: wave (c8 = wv>>1, half = wv&1) covers
  // class c8, comb-half `half`, cols i*64+lane (8 regs/thread, all blocks) ----
  float wcp[8];
  {
    const int c8 = wv >> 1, half = wv & 1;
    const float* Wrow = (c8 < 5) ? (paraW + (size_t)c8 * 1024)
                                 : (chapW + (size_t)(c8 - 5) * 1024);
    #pragma unroll
    for (int i = 0; i < 8; ++i) wcp[i] = Wrow[half * 512 + i * 64 + lane];
  }

  // ---- pin pointwise constants (tid<128 lanes): 16 batches x 8 cols ----
  const int p_lb = tid >> 3, p_u = tid & 7;       // local batch, col-in-group
  const int p_jh = s4d * 8 + p_u;                 // col within gate section
  const int p_batch = mhalf * 16 + (p_lb & 15);
  float bgi = 0.f, bgf = 0.f, bgg = 0.f, bgo = 0.f;
  float creg = 0.f;
  if (tid < 128){
    bgi = biasg[d_dir * G4 + p_jh];
    bgf = biasg[d_dir * G4 + 512 + p_jh];
    bgg = biasg[d_dir * G4 + 1024 + p_jh];
    bgo = biasg[d_dir * G4 + 1536 + p_jh];
  }

  const int abatch = mhalf * 16 + dn;   // this block's D A-row (batch)

  unsigned int bk = 0, gk = 0;

  for (int s = 0; s < NSTEP; ++s){
    const int par = s & 1;

    // ---- prefetch D's x/h A-operands (inputs stable through all of B) ----
    f32x4 xpre[4][2];
    short8 hpreh[4], hprel[4];
    if (wv >= 6 && wv < 12){
      const int ts = d_dir ? (Tz - 1 - s) : s;
      const float* xr = embf + ((size_t)(abatch * Tz + ts)) * Ez;
      #pragma unroll
      for (int kk = 0; kk < 4; ++kk){
        const int e = wv * 128 + kk * 32 + dquad * 8 - 768;
        xpre[kk][0] = *(const f32x4*)(xr + e);
        xpre[kk][1] = *(const f32x4*)(xr + e + 4);
      }
    } else if (wv >= 12){
      const size_t hrow = (((size_t)par * 2 + d_dir) * Bz + abatch) * (size_t)Hz;
      #pragma unroll
      for (int kk = 0; kk < 4; ++kk){
        const int kh = (wv - 12) * 128 + kk * 32 + dquad * 8;
        hpreh[kk] = ald8s(hph + hrow + kh);
        hprel[kk] = ald8s(hpl + hrow + kh);
      }
    }

    // ============ Phase B: dec GEMV + attention for (b_b, t-slice) ============
    {
      // stage h (hi+lo reconstruction, both dirs) into LDS
      if (tid < 512){
        const int dir = tid >> 8, cw = tid & 255;
        const unsigned int wb = (((unsigned)par * 2 + dir) * Bz + b_b) * 256u + cw;
        const unsigned int hiw = ald32(((const unsigned int*)hph) + wb);
        const unsigned int low = ald32(((const unsigned int*)hpl) + wb);
        hs[dir * 512 + 2 * cw]     = b2f((short)(hiw & 0xffffu)) + b2f((short)(low & 0xffffu));
        hs[dir * 512 + 2 * cw + 1] = b2f((short)(hiw >> 16))     + b2f((short)(low >> 16));
      }
      __syncthreads();
      // dec partials from register-pinned dec_W
      {
        const int kc = tid & 15, j2 = tid >> 4;
        float a0 = 0.f, a1 = 0.f;
        #pragma unroll
        for (int i = 0; i < 32; ++i){
          a0 += hs[kc + i * 16] * wreg[i];
          a1 += hs[512 + kc + i * 16] * wreg[i];
        }
        red[kc * 132 + j2] = a0;
        red[kc * 132 + 66 + j2] = a1;
      }
      __syncthreads();
      if (tid < 128){
        const int dir = tid >> 6, j2 = tid & 63;
        float ssum = 0.f;
        #pragma unroll
        for (int i = 0; i < 16; ++i) ssum += red[i * 132 + dir * 66 + j2];
        ast32f(decw + ((size_t)(dir * Bz + b_b)) * Hz + b_q * 64 + j2, ssum + db_r);
      }
      // ---- split group-sync #1: arrive, then hide the out-projection for
      // h_{s-1} (staged in hs) inside the wait window, then poll ----
      __syncthreads();   // drains decw stores before arrival
      ++gk;
      if (tid == 0)
        __hip_atomic_fetch_add(grp + (unsigned)b_b * 16u, 1u,
                               __ATOMIC_RELAXED, __HIP_MEMORY_SCOPE_AGENT);
      if (s > 0 && b_q == (s & 7)){
        // out(b, t, c): fwd half -> t = s-1 ; bwd half -> t = Tz - s.
        // Exclusive owner per (b,t,c,half) across all steps -> plain RMW via
        // agent-scope load/store, zero contention.
        const int half = wv & 1, c8 = wv >> 1;
        float vv = 0.f;
        #pragma unroll
        for (int i = 0; i < 8; ++i)
          vv += hs[half * 512 + i * 64 + lane] * wcp[i];
        vv = wsum(vv);
        if (lane == 0){
          const int ts = half ? (Tz - s) : (s - 1);
          float* po = out + ((size_t)(b_b * Tz + ts)) * 8 + c8;
          ast32f(po, ald32f(po) + vv);
        }
      }
      if (tid == 0){
        while (__hip_atomic_load(grp + (unsigned)b_b * 16u, __ATOMIC_RELAXED,
                                 __HIP_MEMORY_SCOPE_AGENT) < 8u * gk)
          __builtin_amdgcn_s_sleep(1);
      }
      __syncthreads();

      // stage full dec (both dirs) into LDS
      decs[tid] = ald32f(decw + (((size_t)(tid >> 9)) * Bz + b_b) * Hz + (tid & 511));
      __syncthreads();
      float dff[8], dfb[8];
      #pragma unroll
      for (int j = 0; j < 8; ++j){
        dff[j] = decs[j * 64 + lane];
        dfb[j] = decs[512 + j * 64 + lane];
      }
      #pragma unroll 1
      for (int i = 0; i < 4; ++i){
        const int tl = wv * 4 + i;
        float sf = 0.f, sb = 0.f;
        #pragma unroll
        for (int j = 0; j < 8; ++j){
          const float e = eps_lds[tl * 512 + j * 64 + lane];
          sf += vr[j] * fast_tanh(e + dff[j]);
          sb += vr[j] * fast_tanh(e + dfb[j]);
        }
        sf = wsum(sf); sb = wsum(sb);
        if (lane == 0){ scs[0][tl] = sf; scs[1][tl] = sb; }
      }
      __syncthreads();
      if (wv < 2){
        const float sv = scs[wv][lane];
        const float m = wmaxr(sv);
        const float p = __expf(sv - m);
        const float l = wsum(p);
        pw[wv][lane] = p;
        if (lane == 0){
          ast32f(pstat + (((wv * Bz) + b_b) * 8 + b_q) * 2 + 0, m);
          ast32f(pstat + (((wv * Bz) + b_b) * 8 + b_q) * 2 + 1, l);
        }
      }
      __syncthreads();
      // partial ctx: u32 loads, 2 adjacent bf16 cols per thread
      if (lane < 24){
        const int e2 = wv * 24 + lane;   // u32 col index, 0..383
        const unsigned int* eb =
            (const unsigned int*)(emb16 + ((size_t)(b_b * Tz + t0)) * Ez) + e2;
        float aF0 = 0.f, aF1 = 0.f, aB0 = 0.f, aB1 = 0.f;
        #pragma unroll 8
        for (int t = 0; t < 64; ++t){
          const unsigned int u = eb[(size_t)t * 384];
          const float x0 = b2f((short)(u & 0xffffu));
          const float x1 = b2f((short)(u >> 16));
          const float w0 = pw[0][t], w1 = pw[1][t];
          aF0 += w0 * x0; aF1 += w0 * x1;
          aB0 += w1 * x0; aB1 += w1 * x1;
        }
        const int e = 2 * e2;
        float* p0 = pctx + ((size_t)(0 * Bz + b_b) * 8 + b_q) * Ez + e;
        float* p1 = pctx + ((size_t)(1 * Bz + b_b) * 8 + b_q) * Ez + e;
        ast32f(p0, aF0); ast32f(p0 + 1, aF1);
        ast32f(p1, aB0); ast32f(p1 + 1, aB1);
      }
      ++gk; gsync(grp, b_b, gk, tid);   // stats + partials ready

      // fac: parallel across 16 lanes (dir = lane>>3, qq = lane&7)
      if (tid < 16){
        const int dir = tid >> 3, qq = tid & 7;
        const float m = ald32f(pstat + (((dir * Bz) + b_b) * 8 + qq) * 2 + 0);
        const float l = ald32f(pstat + (((dir * Bz) + b_b) * 8 + qq) * 2 + 1);
        float M = m;
        #pragma unroll
        for (int o = 1; o < 8; o <<= 1) M = fmaxf(M, __shfl_xor(M, o, 8));
        const float term = l * __expf(m - M);
        float L = term;
        #pragma unroll
        for (int o = 1; o < 8; o <<= 1) L += __shfl_xor(L, o, 8);
        fac[dir][qq] = __expf(m - M) / L;
      }
      __syncthreads();
      // combine ctx cols [q*96, q*96+96) for both dirs (2 cols/thread)
      if (tid < 96){
        const int dir = tid / 48, p = tid % 48;
        const int e = b_q * 96 + 2 * p;
        float s0 = 0.f, s1 = 0.f;
        #pragma unroll
        for (int qq = 0; qq < 8; ++qq){
          const float fq = fac[dir][qq];
          const float* pb = pctx + ((size_t)(dir * Bz + b_b) * 8 + qq) * Ez + e;
          s0 += ald32f(pb) * fq;
          s1 += ald32f(pb + 1) * fq;
        }
        const unsigned int u0 = pk(s0), u1 = pk(s1);
        const unsigned wi = (((unsigned)(dir * Bz + b_b)) * AK + (unsigned)e) >> 1;
        ast32(((unsigned int*)amathi) + wi, (u0 >> 16) | (u1 & 0xffff0000u));
        ast32(((unsigned int*)amatlo) + wi, (u0 & 0xffffu) | ((u1 & 0xffffu) << 16));
      }
    }
    // ---- gbar#1 split: arrive, zero gateval in the wait window, wait ----
    ++bk;
    __syncthreads();
    gbar_arrive(sub, top, flags, bk, blk, tid);
    if (tid < 512) gateval[tid] = 0.f;
    gbar_wait(flags, bk, blk, tid);

    // ============ Phase D: gates via split-bf16 MFMA + pointwise LSTM ============
    {
      const int dir = d_dir;
      f32x4 C0 = {0.f, 0.f, 0.f, 0.f}, C1 = {0.f, 0.f, 0.f, 0.f};
      if (wv < 6){
        // ctx region from amat (sc reads; written this step by B)
        const size_t arow = ((size_t)(dir * Bz) + abatch) * AK;
        #pragma unroll
        for (int kk = 0; kk < 4; ++kk){
          const int k = wv * 128 + kk * 32 + dquad * 8;
          const short8 Ah = ald8s(amathi + arow + k);
          const short8 Al = ald8s(amatlo + arow + k);
          C0 = __builtin_amdgcn_mfma_f32_16x16x32_bf16(Ah, Bfrag[kk][0], C0, 0, 0, 0);
          C0 = __builtin_amdgcn_mfma_f32_16x16x32_bf16(Al, Bfrag[kk][0], C0, 0, 0, 0);
          C1 = __builtin_amdgcn_mfma_f32_16x16x32_bf16(Ah, Bfrag[kk][1], C1, 0, 0, 0);
          C1 = __builtin_amdgcn_mfma_f32_16x16x32_bf16(Al, Bfrag[kk][1], C1, 0, 0, 0);
        }
      } else if (wv < 12){
        // x_t region from registers prefetched at B start (CONST embf)
        #pragma unroll
        for (int kk = 0; kk < 4; ++kk){
          const f32x4 x0 = xpre[kk][0];
          const f32x4 x1 = xpre[kk][1];
          short8 Ah, Al;
          #pragma unroll
          for (int j = 0; j < 4; ++j){
            const unsigned short h0 = f2b(x0[j]);
            Ah[j] = (short)h0; Al[j] = (short)f2b(x0[j] - b2f((short)h0));
            const unsigned short h1 = f2b(x1[j]);
            Ah[4 + j] = (short)h1; Al[4 + j] = (short)f2b(x1[j] - b2f((short)h1));
          }
          C0 = __builtin_amdgcn_mfma_f32_16x16x32_bf16(Ah, Bfrag[kk][0], C0, 0, 0, 0);
          C0 = __builtin_amdgcn_mfma_f32_16x16x32_bf16(Al, Bfrag[kk][0], C0, 0, 0, 0);
          C1 = __builtin_amdgcn_mfma_f32_16x16x32_bf16(Ah, Bfrag[kk][1], C1, 0, 0, 0);
          C1 = __builtin_amdgcn_mfma_f32_16x16x32_bf16(Al, Bfrag[kk][1], C1, 0, 0, 0);
        }
      } else {
        // h region from registers prefetched at B start (hp[par], stable)
        #pragma unroll
        for (int kk = 0; kk < 4; ++kk){
          C0 = __builtin_amdgcn_mfma_f32_16x16x32_bf16(hpreh[kk], Bfrag[kk][0], C0, 0, 0, 0);
          C0 = __builtin_amdgcn_mfma_f32_16x16x32_bf16(hprel[kk], Bfrag[kk][0], C0, 0, 0, 0);
          C1 = __builtin_amdgcn_mfma_f32_16x16x32_bf16(hpreh[kk], Bfrag[kk][1], C1, 0, 0, 0);
          C1 = __builtin_amdgcn_mfma_f32_16x16x32_bf16(hprel[kk], Bfrag[kk][1], C1, 0, 0, 0);
        }
      }
      // gateval[local_batch][32]: col-unit = (dn>>2)*8 + j*4 + (dn&3)
      #pragma unroll
      for (int r = 0; r < 4; ++r){
        const int rowb = (dquad * 4 + r) * 32 + (dn >> 2) * 8 + (dn & 3);
        unsafeAtomicAdd(&gateval[rowb],     C0[r]);
        unsafeAtomicAdd(&gateval[rowb + 4], C1[r]);
      }
      __syncthreads();
      if (tid < 128){
        const float gi = gateval[p_lb * 32 + p_u]       + bgi;
        const float gf = gateval[p_lb * 32 + 8 + p_u]   + bgf;
        const float gg = gateval[p_lb * 32 + 16 + p_u]  + bgg;
        const float go = gateval[p_lb * 32 + 24 + p_u]  + bgo;
        const float cnew = sigf(gf) * creg + sigf(gi) * fast_tanh(gg);
        const float hval = sigf(go) * fast_tanh(cnew);
        creg = cnew;
        // direct h handoff into the next-step parity buffer (hi/lo packed)
        const unsigned int u = pk(hval);
        const unsigned int up = __shfl_xor((int)u, 1, 64);
        if ((p_u & 1) == 0){
          const unsigned int hiw = (u >> 16) | (up & 0xffff0000u);
          const unsigned int low = (u & 0xffffu) | ((up & 0xffffu) << 16);
          const unsigned wi = ((((unsigned)(par ^ 1) * 2 + d_dir) * Bz + p_batch) * 256u)
                              + ((unsigned)p_jh >> 1);
          ast32(((unsigned int*)hph) + wi, hiw);
          ast32(((unsigned int*)hpl) + wi, low);
        }
      }
    }
    // ---- gbar#2 ----
    ++bk;
    __syncthreads();
    gbar_arrive(sub, top, flags, bk, blk, tid);
    gbar_wait(flags, bk, blk, tid);
  }

  // ---- epilogue: out-projection for h_511 (fwd t=511, bwd t=0) ----
  // Final gbar above made D(511)'s hp[0] writes visible grid-wide.
  if (b_q == 0){
    if (tid < 512){
      const int dir = tid >> 8, cw = tid & 255;
      const unsigned int wb = ((unsigned)dir * Bz + b_b) * 256u + cw;  // par=0
      const unsigned int hiw = ald32(((const unsigned int*)hph) + wb);
      const unsigned int low = ald32(((const unsigned int*)hpl) + wb);
      hs[dir * 512 + 2 * cw]     = b2f((short)(hiw & 0xffffu)) + b2f((short)(low & 0xffffu));
      hs[dir * 512 + 2 * cw + 1] = b2f((short)(hiw >> 16))     + b2f((short)(low >> 16));
    }
    __syncthreads();
    const int half = wv & 1, c8 = wv >> 1;
    float vv = 0.f;
    #pragma unroll
    for (int i = 0; i < 8; ++i)
      vv += hs[half * 512 + i * 64 + lane] * wcp[i];
    vv = wsum(vv);
    if (lane == 0){
      const int ts = half ? 0 : (Tz - 1);
      float* po = out + ((size_t)(b_b * Tz + ts)) * 8 + c8;
      ast32f(po, ald32f(po) + vv);
    }
  }
}

extern "C" void kernel_launch(void* const* d_in, const int* in_sizes, int n_in,
                              void* d_out, int out_size, void* d_ws, size_t ws_size,
                              hipStream_t stream) {
  (void)in_sizes; (void)n_in; (void)out_size; (void)ws_size;
  const float* emb    = (const float*)d_in[0];
  const float* Wih_f  = (const float*)d_in[1];
  const float* Whh_f  = (const float*)d_in[2];
  const float* bih_f  = (const float*)d_in[3];
  const float* bhh_f  = (const float*)d_in[4];
  const float* Wih_b  = (const float*)d_in[5];
  const float* Whh_b  = (const float*)d_in[6];
  const float* bih_b  = (const float*)d_in[7];
  const float* bhh_b  = (const float*)d_in[8];
  const float* enc_W  = (const float*)d_in[9];
  const float* enc_b  = (const float*)d_in[10];
  const float* dec_W  = (const float*)d_in[11];
  const float* dec_b  = (const float*)d_in[12];
  const float* vvec   = (const float*)d_in[13];
  const float* paraW  = (const float*)d_in[14];
  const float* parab  = (const float*)d_in[15];
  const float* chapW  = (const float*)d_in[16];
  const float* chapb  = (const float*)d_in[17];
  float* out = (float*)d_out;

  uint8_t* w = (uint8_t*)d_ws;
  unsigned int* sub   = (unsigned int*)(w + OFF_SUB);
  unsigned int* grp   = (unsigned int*)(w + OFF_GRP);
  unsigned int* flags = (unsigned int*)(w + OFF_FLAGS);
  unsigned int* top   = (unsigned int*)(w + OFF_TOP);
  unsigned short* amathi = (unsigned short*)(w + OFF_AMATH);
  unsigned short* amatlo = (unsigned short*)(w + OFF_AMATL);
  unsigned short* hph    = (unsigned short*)(w + OFF_HPH);
  unsigned short* hpl    = (unsigned short*)(w + OFF_HPL);
  float* decw   = (float*)(w + OFF_DEC);
  float* pstat  = (float*)(w + OFF_PSTAT);
  float* biasg  = (float*)(w + OFF_BIASG);
  float* pctx   = (float*)(w + OFF_PCTX);
  unsigned short* emb16  = (unsigned short*)(w + OFF_EMB16);
  float* ep32   = (float*)(w + OFF_EP32);
  unsigned short* wih16 = (unsigned short*)(w + OFF_WIH);
  unsigned short* whh16 = (unsigned short*)(w + OFF_WHH);
  unsigned short* wenchi = (unsigned short*)(w + OFF_WENCHI);
  unsigned short* wenclo = (unsigned short*)(w + OFF_WENCLO);

  // zero control/state region (barriers, flags, group counters, amat, hp)
  hipMemsetAsync(d_ws, 0, CTRL_BYTES, stream);

  // weight converts (gate weights bf16-hi only; enc split for fp32-accurate ep)
  cvtk<<<512, 256, 0, stream>>>(Wih_f, wih16,               G4 * 2 * Ez);
  cvtk<<<512, 256, 0, stream>>>(Wih_b, wih16 + G4 * 2 * Ez, G4 * 2 * Ez);
  cvtk<<<256, 256, 0, stream>>>(Whh_f, whh16,               G4 * Hz);
  cvtk<<<256, 256, 0, stream>>>(Whh_b, whh16 + G4 * Hz,     G4 * Hz);
  splitk<<<256, 256, 0, stream>>>(enc_W, wenchi, wenclo, Hz * Ez);
  cvtk<<<1024, 256, 0, stream>>>(emb, emb16, Bz * Tz * Ez);
  biask<<<16, 256, 0, stream>>>(bih_f, bhh_f, bih_b, bhh_b, biasg);

  // enc_proj (fp32-accurate split-bf16 MFMA) — wenc aliases the scan-only
  // pctx region, which the scan writes before reading, so ordering is safe
  encgemm<<<256, 256, 0, stream>>>(emb, wenchi, wenclo, enc_b, ep32);

  // out = bias (scan accumulates exclusive-owner contributions)
  outinit<<<512, 256, 0, stream>>>(out, parab, chapb);

  // persistent bidirectional attention-LSTM scan
  scan_kernel<<<NBLK, 1024, 0, stream>>>(
      sub, top, flags, grp, amathi, amatlo, hph, hpl, decw, pctx, pstat, biasg,
      emb, emb16, ep32, wih16, whh16,
      dec_W, dec_b, vvec, paraW, chapW, out);
}

// Round 7
// 35033.316 us; speedup vs baseline: 1.1162x; 1.1162x over previous
//
#include <hip/hip_runtime.h>
#include <stdint.h>

// Problem sizes
#define Bz 32
#define Tz 512
#define Ez 768
#define Hz 512
#define G4 2048      // 4*H
#define AK 768       // staged A-matrix: ctx cols only (x read direct, h in parity bufs)
#define NBLK 256
#define NSTEP 512

typedef __attribute__((ext_vector_type(8))) short short8;
typedef __attribute__((ext_vector_type(4))) float f32x4;

// ---------------- ws layout (bytes) — total identical to proven 77881344 ----------------
#define OFF_SUB    0u            // 32 sub-barrier counters, 64B padded
#define OFF_GRP    2048u         // 32 group counters, 64B padded
#define OFF_AMATH  4096u         // 64*768 bf16 = 98304 (ctx only)
#define OFF_AMATL  102400u       // 98304 -> ends 200704
#define OFF_FLAGS  200704u       // 32 release-flag lines = 2048 -> ends 202752
#define OFF_TOP    202752u       // top counter, own line (slack to 397312)
#define OFF_HPH    397312u       // 2par*2dir*32*512 bf16 hi = 131072
#define OFF_HPL    528384u       // 131072
#define CTRL_BYTES 659456u       // memset-0: sub/grp/amat/flags/top/hp
#define OFF_DEC    659456u       // 2*32*512 f32 = 131072 (write-before-read)
#define OFF_PSTAT  790528u       // 2*32*8*2 f32 = 4096
#define OFF_BIASG  794624u       // 2*2048 f32 = 16384
#define OFF_PCTX   811008u       // 2*32*8*768 f32 = 1572864
#define OFF_EMB16  2383872u      // 32*512*768 bf16 = 25165824
#define OFF_EP32   27549696u     // 32*512*512 f32 = 33554432
#define OFF_WIH    61104128u     // 2*2048*1536 bf16 = 12582912
#define OFF_WHH    73687040u     // 2*2048*512 bf16 = 4194304
// wenc hi/lo alias the scan-only pctx region (encgemm finishes before scan writes pctx)
#define OFF_WENCHI OFF_PCTX
#define OFF_WENCLO (OFF_PCTX + 786432u)
#define WS_NEEDED  77881344u     // == proven footprint of the passing kernel

__device__ __forceinline__ float b2f(short s){
  union { unsigned int u; float f; } w;
  w.u = ((unsigned int)(unsigned short)s) << 16;
  return w.f;
}
__device__ __forceinline__ unsigned short f2b(float f){
  union { float f; unsigned int u; } w; w.f = f;
  unsigned int u = w.u;
  return (unsigned short)((u + 0x7fffu + ((u >> 16) & 1u)) >> 16);
}
__device__ __forceinline__ unsigned int pk(float x){
  const unsigned short h = f2b(x);
  const unsigned short l = f2b(x - b2f((short)h));
  return ((unsigned int)h << 16) | (unsigned int)l;
}
__device__ __forceinline__ float fast_tanh(float x){
  float e = __expf(2.f * x);
  return 1.f - 2.f / (e + 1.f);
}
__device__ __forceinline__ float sigf(float x){
  return 1.f / (1.f + __expf(-x));
}
__device__ __forceinline__ float wsum(float v){
  #pragma unroll
  for (int o = 32; o > 0; o >>= 1) v += __shfl_xor(v, o, 64);
  return v;
}
__device__ __forceinline__ float wmaxr(float v){
  #pragma unroll
  for (int o = 32; o > 0; o >>= 1) v = fmaxf(v, __shfl_xor(v, o, 64));
  return v;
}

// relaxed agent-scope atomic access (sc-flagged; bypasses non-coherent L2)
__device__ __forceinline__ unsigned int ald32(const unsigned int* p){
  return __hip_atomic_load(p, __ATOMIC_RELAXED, __HIP_MEMORY_SCOPE_AGENT);
}
__device__ __forceinline__ float ald32f(const float* p){
  return __hip_atomic_load(p, __ATOMIC_RELAXED, __HIP_MEMORY_SCOPE_AGENT);
}
__device__ __forceinline__ unsigned long long ald64(const unsigned long long* p){
  return __hip_atomic_load(p, __ATOMIC_RELAXED, __HIP_MEMORY_SCOPE_AGENT);
}
__device__ __forceinline__ void ast32(unsigned int* p, unsigned int v){
  __hip_atomic_store(p, v, __ATOMIC_RELAXED, __HIP_MEMORY_SCOPE_AGENT);
}
__device__ __forceinline__ void ast32f(float* p, float v){
  __hip_atomic_store(p, v, __ATOMIC_RELAXED, __HIP_MEMORY_SCOPE_AGENT);
}
__device__ __forceinline__ short8 ald8s(const unsigned short* p){
  union { unsigned long long u[2]; short8 s; } w;
  const unsigned long long* q = (const unsigned long long*)p;
  w.u[0] = ald64(q);
  w.u[1] = ald64(q + 1);
  return w.s;
}

// Grid barrier, split arrive/wait. Arrival: 32 sub-counters (8 blocks each)
// -> top counter -> release written to 32 SEPARATE flag lines (pollers never
// share a line with arrival RMWs). Window work can be placed between arrive
// and wait. Fence-free: __syncthreads drains vmcnt per wave before s_barrier.
__device__ __forceinline__ void gbar_arrive(unsigned int* sub, unsigned int* top,
                                            unsigned int* flags, unsigned int bk,
                                            int blk, int tid){
  if (tid == 0){
    const unsigned int o =
        __hip_atomic_fetch_add(sub + (unsigned)(blk >> 3) * 16u, 1u,
                               __ATOMIC_RELAXED, __HIP_MEMORY_SCOPE_AGENT);
    if (o == 8u * bk - 1u){
      const unsigned int t =
          __hip_atomic_fetch_add(top, 1u, __ATOMIC_RELAXED,
                                 __HIP_MEMORY_SCOPE_AGENT);
      if (t == 32u * bk - 1u){
        #pragma unroll
        for (int i = 0; i < 32; ++i)
          __hip_atomic_store(flags + i * 16, bk, __ATOMIC_RELAXED,
                             __HIP_MEMORY_SCOPE_AGENT);
      }
    }
  }
}
__device__ __forceinline__ void gbar_wait(unsigned int* flags, unsigned int bk,
                                          int blk, int tid){
  if (tid == 0){
    while (__hip_atomic_load(flags + (unsigned)(blk >> 3) * 16u,
                             __ATOMIC_RELAXED, __HIP_MEMORY_SCOPE_AGENT) < bk)
      __builtin_amdgcn_s_sleep(2);
  }
  __syncthreads();
}

// 8-block batch-group sync (cumulative counter, target 8*gk)
__device__ __forceinline__ void gsync(unsigned int* grp, int b,
                                      unsigned int gk, int tid){
  __syncthreads();
  if (tid == 0){
    __hip_atomic_fetch_add(grp + (unsigned)b * 16u, 1u,
                           __ATOMIC_RELAXED, __HIP_MEMORY_SCOPE_AGENT);
    while (__hip_atomic_load(grp + (unsigned)b * 16u, __ATOMIC_RELAXED,
                             __HIP_MEMORY_SCOPE_AGENT) < 8u * gk)
      __builtin_amdgcn_s_sleep(1);
  }
  __syncthreads();
}

// ---------------- fp32 -> bf16 convert ----------------
__global__ void cvtk(const float* __restrict__ src, unsigned short* __restrict__ dst, int n){
  int i = blockIdx.x * blockDim.x + threadIdx.x;
  const int stride = gridDim.x * blockDim.x;
  for (; i < n; i += stride) dst[i] = f2b(src[i]);
}

// fp32 -> (hi, lo) bf16 Dekker split
__global__ void splitk(const float* __restrict__ src, unsigned short* __restrict__ hi,
                       unsigned short* __restrict__ lo, int n){
  int i = blockIdx.x * blockDim.x + threadIdx.x;
  const int stride = gridDim.x * blockDim.x;
  for (; i < n; i += stride){
    const float x = src[i];
    const unsigned short h = f2b(x);
    hi[i] = h;
    lo[i] = f2b(x - b2f((short)h));
  }
}

// bias_g[dir][j] = bih[j] + bhh[j]
__global__ void biask(const float* bihf, const float* bhhf,
                      const float* bihb, const float* bhhb, float* bg){
  int i = blockIdx.x * blockDim.x + threadIdx.x;
  if (i < G4) bg[i] = bihf[i] + bhhf[i];
  else if (i < 2 * G4) bg[i] = bihb[i - G4] + bhhb[i - G4];
}

// out[b][t][c] = bias_c (exclusive-owner accumulates happen in the scan)
__global__ void outinit(float* out, const float* parab, const float* chapb){
  const int i = blockIdx.x * blockDim.x + threadIdx.x;
  if (i < Bz * Tz * 8){
    const int c = i & 7;
    out[i] = (c < 5) ? parab[c] : chapb[c - 5];
  }
}

// ---------------- enc_proj GEMM (split-bf16, fp32-accurate) ----------------
__global__ __launch_bounds__(256, 1) void encgemm(
    const float* __restrict__ embf,
    const unsigned short* __restrict__ wenchi, const unsigned short* __restrict__ wenclo,
    const float* __restrict__ encb, float* __restrict__ ep32)
{
  const int lane = threadIdx.x & 63, wvv = threadIdx.x >> 6;
  const int mt = blockIdx.x * 4 + wvv;
  const int m0 = mt * 16;
  const int n = lane & 15, quad = lane >> 4;
  f32x4 acc[32];
  #pragma unroll
  for (int i = 0; i < 32; ++i) acc[i] = (f32x4){0.f, 0.f, 0.f, 0.f};
  const float* ar = embf + ((size_t)(m0 + n)) * Ez;
  for (int kk = 0; kk < 24; ++kk){
    const int k = kk * 32 + quad * 8;
    const f32x4 a0 = *(const f32x4*)(ar + k);
    const f32x4 a1 = *(const f32x4*)(ar + k + 4);
    short8 ah, al;
    #pragma unroll
    for (int j = 0; j < 4; ++j){
      unsigned short h0 = f2b(a0[j]);
      ah[j] = (short)h0; al[j] = (short)f2b(a0[j] - b2f((short)h0));
      unsigned short h1 = f2b(a1[j]);
      ah[4 + j] = (short)h1; al[4 + j] = (short)f2b(a1[j] - b2f((short)h1));
    }
    #pragma unroll
    for (int nt = 0; nt < 32; ++nt){
      const size_t bo = ((size_t)(nt * 16 + n)) * Ez + k;
      const short8 bh = *(const short8*)(wenchi + bo);
      const short8 bl = *(const short8*)(wenclo + bo);
      acc[nt] = __builtin_amdgcn_mfma_f32_16x16x32_bf16(ah, bh, acc[nt], 0, 0, 0);
      acc[nt] = __builtin_amdgcn_mfma_f32_16x16x32_bf16(ah, bl, acc[nt], 0, 0, 0);
      acc[nt] = __builtin_amdgcn_mfma_f32_16x16x32_bf16(al, bh, acc[nt], 0, 0, 0);
    }
  }
  #pragma unroll
  for (int nt = 0; nt < 32; ++nt){
    const int colg = nt * 16 + n;
    const float bb = encb[colg];
    #pragma unroll
    for (int r = 0; r < 4; ++r){
      const int row = m0 + quad * 4 + r;
      ep32[(size_t)row * Hz + colg] = acc[nt][r] + bb;
    }
  }
}

// ---------------- persistent scan kernel ----------------
// __launch_bounds__(1024, 4): LDS (151 KB) caps us at 1 block/CU = 4 waves/EU
// anyway; declaring it raises the VGPR cap 64 -> 128 so the D-operand
// prefetch fits in registers (round 6 spilled to scratch at the default cap:
// WRITE_SIZE 1.2e6 -> 6.25e6 KB, +13 GB/dispatch HBM).
__global__ __launch_bounds__(1024, 4) void scan_kernel(
    unsigned int* sub, unsigned int* top, unsigned int* flags, unsigned int* grp,
    unsigned short* amathi, unsigned short* amatlo,
    unsigned short* hph, unsigned short* hpl,
    float* decw, float* pctx, float* pstat,
    const float* __restrict__ biasg,
    const float* __restrict__ embf, const unsigned short* __restrict__ emb16,
    const float* __restrict__ ep32,
    const unsigned short* __restrict__ wih16, const unsigned short* __restrict__ whh16,
    const float* __restrict__ decWf, const float* __restrict__ decbias,
    const float* __restrict__ vvec,
    const float* __restrict__ paraW, const float* __restrict__ chapW,
    float* __restrict__ out)
{
  __shared__ float eps_lds[64 * 512];   // 128 KB enc_proj slice, resident all steps
  __shared__ float hs[1024];            // staged h (both dirs, this batch)
  __shared__ float red[2112];           // dec partial reduce (16 k-chunks x 2dir x 64, padded)
  __shared__ float decs[1024];          // dec for this block's batch, both dirs
  __shared__ float scs[2][64];
  __shared__ float pw[2][64];
  __shared__ float fac[2][8];
  __shared__ float gateval[512];        // 16 batches x 32 col-units

  const int blk = blockIdx.x;
  const int tid = threadIdx.x;
  const int lane = tid & 63, wv = tid >> 6;

  const int d_dir = blk >> 7, mhalf = (blk >> 6) & 1, s4d = blk & 63;  // phase-D role
  const int b_b = blk >> 3, b_q = blk & 7;        // phase-B role (batch, t-slice)
  const int t0 = b_q * 64;

  // ---- preload ep slice into LDS (resident for all 512 steps) ----
  for (int i = tid; i < 8192; i += 1024){
    const int row = i >> 7;
    const int c4 = (i & 127) << 2;
    *(f32x4*)&eps_lds[row * 512 + c4] =
        *(const f32x4*)(ep32 + ((size_t)(b_b * Tz + t0 + row)) * Hz + c4);
  }
  // v in stride-64 lane layout (conflict-free score loop)
  float vr[8];
  #pragma unroll
  for (int j = 0; j < 8; ++j) vr[j] = vvec[j * 64 + lane];

  // ---- pin phase-D B-weight fragments in registers (same 256B every step) ----
  const int dn = lane & 15, dquad = lane >> 4;
  short8 Bfrag[4][2];
  #pragma unroll
  for (int kk = 0; kk < 4; ++kk){
    const int k = wv * 128 + kk * 32 + dquad * 8;
    #pragma unroll
    for (int j = 0; j < 2; ++j){
      const int coln = ((dn >> 2) * 512) + s4d * 8 + j * 4 + (dn & 3);
      Bfrag[kk][j] = (k < 1536)
        ? *(const short8*)(wih16 + ((size_t)(d_dir * G4) + coln) * 1536 + k)
        : *(const short8*)(whh16 + ((size_t)(d_dir * G4) + coln) * 512 + (k - 1536));
    }
  }
  // ---- pin dec_W slice in registers: thread (j2 = tid>>4, kc = tid&15)
  // covers row (b_q*64+j2), k in {kc, kc+16, ..., kc+496} ----
  float wreg[32];
  {
    const float* wrow = decWf + ((size_t)(b_q * 64 + (tid >> 4))) * Hz + (tid & 15);
    #pragma unroll
    for (int i = 0; i < 32; ++i) wreg[i] = wrow[i * 16];
  }
  float db_r = 0.f;
  if (tid < 128) db_r = decbias[b_q * 64 + (tid & 63)];

  // ---- pin out-projection weights: wave (c8 = wv>>1, half = wv&1) covers
  // class c8, comb-half `half`, cols i*64+lane (8 regs/thread, all blocks) ----
  float wcp[8];
  {
    const int c8 = wv >> 1, half = wv & 1;
    const float* Wrow = (c8 < 5) ? (paraW + (size_t)c8 * 1024)
                                 : (chapW + (size_t)(c8 - 5) * 1024);
    #pragma unroll
    for (int i = 0; i < 8; ++i) wcp[i] = Wrow[half * 512 + i * 64 + lane];
  }

  // ---- pin pointwise constants (tid<128 lanes): 16 batches x 8 cols ----
  const int p_lb = tid >> 3, p_u = tid & 7;       // local batch, col-in-group
  const int p_jh = s4d * 8 + p_u;                 // col within gate section
  const int p_batch = mhalf * 16 + (p_lb & 15);
  float bgi = 0.f, bgf = 0.f, bgg = 0.f, bgo = 0.f;
  float creg = 0.f;
  if (tid < 128){
    bgi = biasg[d_dir * G4 + p_jh];
    bgf = biasg[d_dir * G4 + 512 + p_jh];
    bgg = biasg[d_dir * G4 + 1024 + p_jh];
    bgo = biasg[d_dir * G4 + 1536 + p_jh];
  }

  const int abatch = mhalf * 16 + dn;   // this block's D A-row (batch)

  unsigned int bk = 0, gk = 0;

  for (int s = 0; s < NSTEP; ++s){
    const int par = s & 1;

    // ---- prefetch D's x/h A-operands (inputs stable through all of B) ----
    f32x4 xpre[4][2];
    short8 hpreh[4], hprel[4];
    if (wv >= 6 && wv < 12){
      const int ts = d_dir ? (Tz - 1 - s) : s;
      const float* xr = embf + ((size_t)(abatch * Tz + ts)) * Ez;
      #pragma unroll
      for (int kk = 0; kk < 4; ++kk){
        const int e = wv * 128 + kk * 32 + dquad * 8 - 768;
        xpre[kk][0] = *(const f32x4*)(xr + e);
        xpre[kk][1] = *(const f32x4*)(xr + e + 4);
      }
    } else if (wv >= 12){
      const size_t hrow = (((size_t)par * 2 + d_dir) * Bz + abatch) * (size_t)Hz;
      #pragma unroll
      for (int kk = 0; kk < 4; ++kk){
        const int kh = (wv - 12) * 128 + kk * 32 + dquad * 8;
        hpreh[kk] = ald8s(hph + hrow + kh);
        hprel[kk] = ald8s(hpl + hrow + kh);
      }
    }

    // ============ Phase B: dec GEMV + attention for (b_b, t-slice) ============
    {
      // stage h (hi+lo reconstruction, both dirs) into LDS
      if (tid < 512){
        const int dir = tid >> 8, cw = tid & 255;
        const unsigned int wb = (((unsigned)par * 2 + dir) * Bz + b_b) * 256u + cw;
        const unsigned int hiw = ald32(((const unsigned int*)hph) + wb);
        const unsigned int low = ald32(((const unsigned int*)hpl) + wb);
        hs[dir * 512 + 2 * cw]     = b2f((short)(hiw & 0xffffu)) + b2f((short)(low & 0xffffu));
        hs[dir * 512 + 2 * cw + 1] = b2f((short)(hiw >> 16))     + b2f((short)(low >> 16));
      }
      __syncthreads();
      // dec partials from register-pinned dec_W
      {
        const int kc = tid & 15, j2 = tid >> 4;
        float a0 = 0.f, a1 = 0.f;
        #pragma unroll
        for (int i = 0; i < 32; ++i){
          a0 += hs[kc + i * 16] * wreg[i];
          a1 += hs[512 + kc + i * 16] * wreg[i];
        }
        red[kc * 132 + j2] = a0;
        red[kc * 132 + 66 + j2] = a1;
      }
      __syncthreads();
      if (tid < 128){
        const int dir = tid >> 6, j2 = tid & 63;
        float ssum = 0.f;
        #pragma unroll
        for (int i = 0; i < 16; ++i) ssum += red[i * 132 + dir * 66 + j2];
        ast32f(decw + ((size_t)(dir * Bz + b_b)) * Hz + b_q * 64 + j2, ssum + db_r);
      }
      // ---- split group-sync #1: arrive, then hide the out-projection for
      // h_{s-1} (staged in hs) inside the wait window, then poll ----
      __syncthreads();   // drains decw stores before arrival
      ++gk;
      if (tid == 0)
        __hip_atomic_fetch_add(grp + (unsigned)b_b * 16u, 1u,
                               __ATOMIC_RELAXED, __HIP_MEMORY_SCOPE_AGENT);
      if (s > 0 && b_q == (s & 7)){
        // out(b, t, c): fwd half -> t = s-1 ; bwd half -> t = Tz - s.
        // Exclusive owner per (b,t,c,half) across all steps -> plain RMW via
        // agent-scope load/store, zero contention.
        const int half = wv & 1, c8 = wv >> 1;
        float vv = 0.f;
        #pragma unroll
        for (int i = 0; i < 8; ++i)
          vv += hs[half * 512 + i * 64 + lane] * wcp[i];
        vv = wsum(vv);
        if (lane == 0){
          const int ts = half ? (Tz - s) : (s - 1);
          float* po = out + ((size_t)(b_b * Tz + ts)) * 8 + c8;
          ast32f(po, ald32f(po) + vv);
        }
      }
      if (tid == 0){
        while (__hip_atomic_load(grp + (unsigned)b_b * 16u, __ATOMIC_RELAXED,
                                 __HIP_MEMORY_SCOPE_AGENT) < 8u * gk)
          __builtin_amdgcn_s_sleep(1);
      }
      __syncthreads();

      // stage full dec (both dirs) into LDS
      decs[tid] = ald32f(decw + (((size_t)(tid >> 9)) * Bz + b_b) * Hz + (tid & 511));
      __syncthreads();
      float dff[8], dfb[8];
      #pragma unroll
      for (int j = 0; j < 8; ++j){
        dff[j] = decs[j * 64 + lane];
        dfb[j] = decs[512 + j * 64 + lane];
      }
      #pragma unroll 1
      for (int i = 0; i < 4; ++i){
        const int tl = wv * 4 + i;
        float sf = 0.f, sb = 0.f;
        #pragma unroll
        for (int j = 0; j < 8; ++j){
          const float e = eps_lds[tl * 512 + j * 64 + lane];
          sf += vr[j] * fast_tanh(e + dff[j]);
          sb += vr[j] * fast_tanh(e + dfb[j]);
        }
        sf = wsum(sf); sb = wsum(sb);
        if (lane == 0){ scs[0][tl] = sf; scs[1][tl] = sb; }
      }
      __syncthreads();
      if (wv < 2){
        const float sv = scs[wv][lane];
        const float m = wmaxr(sv);
        const float p = __expf(sv - m);
        const float l = wsum(p);
        pw[wv][lane] = p;
        if (lane == 0){
          ast32f(pstat + (((wv * Bz) + b_b) * 8 + b_q) * 2 + 0, m);
          ast32f(pstat + (((wv * Bz) + b_b) * 8 + b_q) * 2 + 1, l);
        }
      }
      __syncthreads();
      // partial ctx: u32 loads, 2 adjacent bf16 cols per thread
      if (lane < 24){
        const int e2 = wv * 24 + lane;   // u32 col index, 0..383
        const unsigned int* eb =
            (const unsigned int*)(emb16 + ((size_t)(b_b * Tz + t0)) * Ez) + e2;
        float aF0 = 0.f, aF1 = 0.f, aB0 = 0.f, aB1 = 0.f;
        #pragma unroll 8
        for (int t = 0; t < 64; ++t){
          const unsigned int u = eb[(size_t)t * 384];
          const float x0 = b2f((short)(u & 0xffffu));
          const float x1 = b2f((short)(u >> 16));
          const float w0 = pw[0][t], w1 = pw[1][t];
          aF0 += w0 * x0; aF1 += w0 * x1;
          aB0 += w1 * x0; aB1 += w1 * x1;
        }
        const int e = 2 * e2;
        float* p0 = pctx + ((size_t)(0 * Bz + b_b) * 8 + b_q) * Ez + e;
        float* p1 = pctx + ((size_t)(1 * Bz + b_b) * 8 + b_q) * Ez + e;
        ast32f(p0, aF0); ast32f(p0 + 1, aF1);
        ast32f(p1, aB0); ast32f(p1 + 1, aB1);
      }
      ++gk; gsync(grp, b_b, gk, tid);   // stats + partials ready

      // fac: parallel across 16 lanes (dir = lane>>3, qq = lane&7)
      if (tid < 16){
        const int dir = tid >> 3, qq = tid & 7;
        const float m = ald32f(pstat + (((dir * Bz) + b_b) * 8 + qq) * 2 + 0);
        const float l = ald32f(pstat + (((dir * Bz) + b_b) * 8 + qq) * 2 + 1);
        float M = m;
        #pragma unroll
        for (int o = 1; o < 8; o <<= 1) M = fmaxf(M, __shfl_xor(M, o, 8));
        const float term = l * __expf(m - M);
        float L = term;
        #pragma unroll
        for (int o = 1; o < 8; o <<= 1) L += __shfl_xor(L, o, 8);
        fac[dir][qq] = __expf(m - M) / L;
      }
      __syncthreads();
      // combine ctx cols [q*96, q*96+96) for both dirs (2 cols/thread)
      if (tid < 96){
        const int dir = tid / 48, p = tid % 48;
        const int e = b_q * 96 + 2 * p;
        float s0 = 0.f, s1 = 0.f;
        #pragma unroll
        for (int qq = 0; qq < 8; ++qq){
          const float fq = fac[dir][qq];
          const float* pb = pctx + ((size_t)(dir * Bz + b_b) * 8 + qq) * Ez + e;
          s0 += ald32f(pb) * fq;
          s1 += ald32f(pb + 1) * fq;
        }
        const unsigned int u0 = pk(s0), u1 = pk(s1);
        const unsigned wi = (((unsigned)(dir * Bz + b_b)) * AK + (unsigned)e) >> 1;
        ast32(((unsigned int*)amathi) + wi, (u0 >> 16) | (u1 & 0xffff0000u));
        ast32(((unsigned int*)amatlo) + wi, (u0 & 0xffffu) | ((u1 & 0xffffu) << 16));
      }
    }
    // ---- gbar#1 split: arrive, zero gateval in the wait window, wait ----
    ++bk;
    __syncthreads();
    gbar_arrive(sub, top, flags, bk, blk, tid);
    if (tid < 512) gateval[tid] = 0.f;
    gbar_wait(flags, bk, blk, tid);

    // ============ Phase D: gates via split-bf16 MFMA + pointwise LSTM ============
    {
      const int dir = d_dir;
      f32x4 C0 = {0.f, 0.f, 0.f, 0.f}, C1 = {0.f, 0.f, 0.f, 0.f};
      if (wv < 6){
        // ctx region from amat (sc reads; written this step by B)
        const size_t arow = ((size_t)(dir * Bz) + abatch) * AK;
        #pragma unroll
        for (int kk = 0; kk < 4; ++kk){
          const int k = wv * 128 + kk * 32 + dquad * 8;
          const short8 Ah = ald8s(amathi + arow + k);
          const short8 Al = ald8s(amatlo + arow + k);
          C0 = __builtin_amdgcn_mfma_f32_16x16x32_bf16(Ah, Bfrag[kk][0], C0, 0, 0, 0);
          C0 = __builtin_amdgcn_mfma_f32_16x16x32_bf16(Al, Bfrag[kk][0], C0, 0, 0, 0);
          C1 = __builtin_amdgcn_mfma_f32_16x16x32_bf16(Ah, Bfrag[kk][1], C1, 0, 0, 0);
          C1 = __builtin_amdgcn_mfma_f32_16x16x32_bf16(Al, Bfrag[kk][1], C1, 0, 0, 0);
        }
      } else if (wv < 12){
        // x_t region from registers prefetched at B start (CONST embf)
        #pragma unroll
        for (int kk = 0; kk < 4; ++kk){
          const f32x4 x0 = xpre[kk][0];
          const f32x4 x1 = xpre[kk][1];
          short8 Ah, Al;
          #pragma unroll
          for (int j = 0; j < 4; ++j){
            const unsigned short h0 = f2b(x0[j]);
            Ah[j] = (short)h0; Al[j] = (short)f2b(x0[j] - b2f((short)h0));
            const unsigned short h1 = f2b(x1[j]);
            Ah[4 + j] = (short)h1; Al[4 + j] = (short)f2b(x1[j] - b2f((short)h1));
          }
          C0 = __builtin_amdgcn_mfma_f32_16x16x32_bf16(Ah, Bfrag[kk][0], C0, 0, 0, 0);
          C0 = __builtin_amdgcn_mfma_f32_16x16x32_bf16(Al, Bfrag[kk][0], C0, 0, 0, 0);
          C1 = __builtin_amdgcn_mfma_f32_16x16x32_bf16(Ah, Bfrag[kk][1], C1, 0, 0, 0);
          C1 = __builtin_amdgcn_mfma_f32_16x16x32_bf16(Al, Bfrag[kk][1], C1, 0, 0, 0);
        }
      } else {
        // h region from registers prefetched at B start (hp[par], stable)
        #pragma unroll
        for (int kk = 0; kk < 4; ++kk){
          C0 = __builtin_amdgcn_mfma_f32_16x16x32_bf16(hpreh[kk], Bfrag[kk][0], C0, 0, 0, 0);
          C0 = __builtin_amdgcn_mfma_f32_16x16x32_bf16(hprel[kk], Bfrag[kk][0], C0, 0, 0, 0);
          C1 = __builtin_amdgcn_mfma_f32_16x16x32_bf16(hpreh[kk], Bfrag[kk][1], C1, 0, 0, 0);
          C1 = __builtin_amdgcn_mfma_f32_16x16x32_bf16(hprel[kk], Bfrag[kk][1], C1, 0, 0, 0);
        }
      }
      // gateval[local_batch][32]: col-unit = (dn>>2)*8 + j*4 + (dn&3)
      #pragma unroll
      for (int r = 0; r < 4; ++r){
        const int rowb = (dquad * 4 + r) * 32 + (dn >> 2) * 8 + (dn & 3);
        unsafeAtomicAdd(&gateval[rowb],     C0[r]);
        unsafeAtomicAdd(&gateval[rowb + 4], C1[r]);
      }
      __syncthreads();
      if (tid < 128){
        const float gi = gateval[p_lb * 32 + p_u]       + bgi;
        const float gf = gateval[p_lb * 32 + 8 + p_u]   + bgf;
        const float gg = gateval[p_lb * 32 + 16 + p_u]  + bgg;
        const float go = gateval[p_lb * 32 + 24 + p_u]  + bgo;
        const float cnew = sigf(gf) * creg + sigf(gi) * fast_tanh(gg);
        const float hval = sigf(go) * fast_tanh(cnew);
        creg = cnew;
        // direct h handoff into the next-step parity buffer (hi/lo packed)
        const unsigned int u = pk(hval);
        const unsigned int up = __shfl_xor((int)u, 1, 64);
        if ((p_u & 1) == 0){
          const unsigned int hiw = (u >> 16) | (up & 0xffff0000u);
          const unsigned int low = (u & 0xffffu) | ((up & 0xffffu) << 16);
          const unsigned wi = ((((unsigned)(par ^ 1) * 2 + d_dir) * Bz + p_batch) * 256u)
                              + ((unsigned)p_jh >> 1);
          ast32(((unsigned int*)hph) + wi, hiw);
          ast32(((unsigned int*)hpl) + wi, low);
        }
      }
    }
    // ---- gbar#2 ----
    ++bk;
    __syncthreads();
    gbar_arrive(sub, top, flags, bk, blk, tid);
    gbar_wait(flags, bk, blk, tid);
  }

  // ---- epilogue: out-projection for h_511 (fwd t=511, bwd t=0) ----
  // Final gbar above made D(511)'s hp[0] writes visible grid-wide.
  if (b_q == 0){
    if (tid < 512){
      const int dir = tid >> 8, cw = tid & 255;
      const unsigned int wb = ((unsigned)dir * Bz + b_b) * 256u + cw;  // par=0
      const unsigned int hiw = ald32(((const unsigned int*)hph) + wb);
      const unsigned int low = ald32(((const unsigned int*)hpl) + wb);
      hs[dir * 512 + 2 * cw]     = b2f((short)(hiw & 0xffffu)) + b2f((short)(low & 0xffffu));
      hs[dir * 512 + 2 * cw + 1] = b2f((short)(hiw >> 16))     + b2f((short)(low >> 16));
    }
    __syncthreads();
    const int half = wv & 1, c8 = wv >> 1;
    float vv = 0.f;
    #pragma unroll
    for (int i = 0; i < 8; ++i)
      vv += hs[half * 512 + i * 64 + lane] * wcp[i];
    vv = wsum(vv);
    if (lane == 0){
      const int ts = half ? 0 : (Tz - 1);
      float* po = out + ((size_t)(b_b * Tz + ts)) * 8 + c8;
      ast32f(po, ald32f(po) + vv);
    }
  }
}

extern "C" void kernel_launch(void* const* d_in, const int* in_sizes, int n_in,
                              void* d_out, int out_size, void* d_ws, size_t ws_size,
                              hipStream_t stream) {
  (void)in_sizes; (void)n_in; (void)out_size; (void)ws_size;
  const float* emb    = (const float*)d_in[0];
  const float* Wih_f  = (const float*)d_in[1];
  const float* Whh_f  = (const float*)d_in[2];
  const float* bih_f  = (const float*)d_in[3];
  const float* bhh_f  = (const float*)d_in[4];
  const float* Wih_b  = (const float*)d_in[5];
  const float* Whh_b  = (const float*)d_in[6];
  const float* bih_b  = (const float*)d_in[7];
  const float* bhh_b  = (const float*)d_in[8];
  const float* enc_W  = (const float*)d_in[9];
  const float* enc_b  = (const float*)d_in[10];
  const float* dec_W  = (const float*)d_in[11];
  const float* dec_b  = (const float*)d_in[12];
  const float* vvec   = (const float*)d_in[13];
  const float* paraW  = (const float*)d_in[14];
  const float* parab  = (const float*)d_in[15];
  const float* chapW  = (const float*)d_in[16];
  const float* chapb  = (const float*)d_in[17];
  float* out = (float*)d_out;

  uint8_t* w = (uint8_t*)d_ws;
  unsigned int* sub   = (unsigned int*)(w + OFF_SUB);
  unsigned int* grp   = (unsigned int*)(w + OFF_GRP);
  unsigned int* flags = (unsigned int*)(w + OFF_FLAGS);
  unsigned int* top   = (unsigned int*)(w + OFF_TOP);
  unsigned short* amathi = (unsigned short*)(w + OFF_AMATH);
  unsigned short* amatlo = (unsigned short*)(w + OFF_AMATL);
  unsigned short* hph    = (unsigned short*)(w + OFF_HPH);
  unsigned short* hpl    = (unsigned short*)(w + OFF_HPL);
  float* decw   = (float*)(w + OFF_DEC);
  float* pstat  = (float*)(w + OFF_PSTAT);
  float* biasg  = (float*)(w + OFF_BIASG);
  float* pctx   = (float*)(w + OFF_PCTX);
  unsigned short* emb16  = (unsigned short*)(w + OFF_EMB16);
  float* ep32   = (float*)(w + OFF_EP32);
  unsigned short* wih16 = (unsigned short*)(w + OFF_WIH);
  unsigned short* whh16 = (unsigned short*)(w + OFF_WHH);
  unsigned short* wenchi = (unsigned short*)(w + OFF_WENCHI);
  unsigned short* wenclo = (unsigned short*)(w + OFF_WENCLO);

  // zero control/state region (barriers, flags, group counters, amat, hp)
  hipMemsetAsync(d_ws, 0, CTRL_BYTES, stream);

  // weight converts (gate weights bf16-hi only; enc split for fp32-accurate ep)
  cvtk<<<512, 256, 0, stream>>>(Wih_f, wih16,               G4 * 2 * Ez);
  cvtk<<<512, 256, 0, stream>>>(Wih_b, wih16 + G4 * 2 * Ez, G4 * 2 * Ez);
  cvtk<<<256, 256, 0, stream>>>(Whh_f, whh16,               G4 * Hz);
  cvtk<<<256, 256, 0, stream>>>(Whh_b, whh16 + G4 * Hz,     G4 * Hz);
  splitk<<<256, 256, 0, stream>>>(enc_W, wenchi, wenclo, Hz * Ez);
  cvtk<<<1024, 256, 0, stream>>>(emb, emb16, Bz * Tz * Ez);
  biask<<<16, 256, 0, stream>>>(bih_f, bhh_f, bih_b, bhh_b, biasg);

  // enc_proj (fp32-accurate split-bf16 MFMA) — wenc aliases the scan-only
  // pctx region, which the scan writes before reading, so ordering is safe
  encgemm<<<256, 256, 0, stream>>>(emb, wenchi, wenclo, enc_b, ep32);

  // out = bias (scan accumulates exclusive-owner contributions)
  outinit<<<512, 256, 0, stream>>>(out, parab, chapb);

  // persistent bidirectional attention-LSTM scan
  scan_kernel<<<NBLK, 1024, 0, stream>>>(
      sub, top, flags, grp, amathi, amatlo, hph, hpl, decw, pctx, pstat, biasg,
      emb, emb16, ep32, wih16, whh16,
      dec_W, dec_b, vvec, paraW, chapW, out);
}

// Round 8
// 24836.961 us; speedup vs baseline: 1.5744x; 1.4105x over previous
//
#include <hip/hip_runtime.h>
#include <stdint.h>

// Problem sizes
#define Bz 32
#define Tz 512
#define Ez 768
#define Hz 512
#define G4 2048      // 4*H
#define AK 1536      // staged A-matrix K: [ctx(768) | x_t(768)]; h in parity bufs
#define NBLK 256
#define NSTEP 512

typedef __attribute__((ext_vector_type(8))) short short8;
typedef __attribute__((ext_vector_type(4))) float f32x4;

// ---------------- ws layout (bytes) — total 77880384 <= proven 77881344 ----------------
#define OFF_SUB    0u            // 32 sub-barrier counters, 32B stride
#define OFF_GRP    1024u         // 32 group counters, 32B stride
#define OFF_FLAGS  2048u         // 32 release-flag slots, 32B stride (separate from RMW lines)
#define OFF_TOP    3072u         // top counter, own line
#define OFF_AMATH  3136u         // 64*1536 bf16 = 196608 (ctx|x)
#define OFF_AMATL  199744u       // 196608
#define OFF_HPH    396352u       // 2par*2dir*32*512 bf16 hi = 131072
#define OFF_HPL    527424u       // 131072
#define CTRL_BYTES 658496u       // memset-0 (after encgemm): sub/grp/flags/top/amat/hp
#define OFF_DEC    658496u       // 2*32*512 f32 = 131072 (write-before-read each step)
#define OFF_PSTAT  789568u       // 4096
#define OFF_BIASG  793664u       // 16384
#define OFF_PCTX   810048u       // 2*32*8*768 f32 = 1572864
#define OFF_EMB16  2382912u      // 32*512*768 bf16 = 25165824
#define OFF_EP32   27548736u     // 32*512*512 f32 = 33554432
#define OFF_WIH    61103168u     // 12582912
#define OFF_WHH    73686080u     // 4194304 -> ends 77880384
// wenc hi aliases the scan-only amat..dec span (786432 B exactly); lo aliases pctx head.
// encgemm runs BEFORE the ctrl memset and before the scan writes these regions.
#define OFF_WENCHI OFF_AMATH
#define OFF_WENCLO OFF_PCTX
#define WS_NEEDED  77880384u

__device__ __forceinline__ float b2f(short s){
  union { unsigned int u; float f; } w;
  w.u = ((unsigned int)(unsigned short)s) << 16;
  return w.f;
}
__device__ __forceinline__ unsigned short f2b(float f){
  union { float f; unsigned int u; } w; w.f = f;
  unsigned int u = w.u;
  return (unsigned short)((u + 0x7fffu + ((u >> 16) & 1u)) >> 16);
}
__device__ __forceinline__ unsigned int pk(float x){
  const unsigned short h = f2b(x);
  const unsigned short l = f2b(x - b2f((short)h));
  return ((unsigned int)h << 16) | (unsigned int)l;
}
__device__ __forceinline__ float fast_tanh(float x){
  float e = __expf(2.f * x);
  return 1.f - 2.f / (e + 1.f);
}
__device__ __forceinline__ float sigf(float x){
  return 1.f / (1.f + __expf(-x));
}
__device__ __forceinline__ float wsum(float v){
  #pragma unroll
  for (int o = 32; o > 0; o >>= 1) v += __shfl_xor(v, o, 64);
  return v;
}
__device__ __forceinline__ float wmaxr(float v){
  #pragma unroll
  for (int o = 32; o > 0; o >>= 1) v = fmaxf(v, __shfl_xor(v, o, 64));
  return v;
}

// relaxed agent-scope atomic access (sc-flagged; bypasses non-coherent L2)
__device__ __forceinline__ unsigned int ald32(const unsigned int* p){
  return __hip_atomic_load(p, __ATOMIC_RELAXED, __HIP_MEMORY_SCOPE_AGENT);
}
__device__ __forceinline__ float ald32f(const float* p){
  return __hip_atomic_load(p, __ATOMIC_RELAXED, __HIP_MEMORY_SCOPE_AGENT);
}
__device__ __forceinline__ unsigned long long ald64(const unsigned long long* p){
  return __hip_atomic_load(p, __ATOMIC_RELAXED, __HIP_MEMORY_SCOPE_AGENT);
}
__device__ __forceinline__ void ast32(unsigned int* p, unsigned int v){
  __hip_atomic_store(p, v, __ATOMIC_RELAXED, __HIP_MEMORY_SCOPE_AGENT);
}
__device__ __forceinline__ void ast32f(float* p, float v){
  __hip_atomic_store(p, v, __ATOMIC_RELAXED, __HIP_MEMORY_SCOPE_AGENT);
}
__device__ __forceinline__ short8 ald8s(const unsigned short* p){
  union { unsigned long long u[2]; short8 s; } w;
  const unsigned long long* q = (const unsigned long long*)p;
  w.u[0] = ald64(q);
  w.u[1] = ald64(q + 1);
  return w.s;
}

// Grid barrier, split arrive/wait. 32 sub-counters (8 blocks each) -> top
// counter -> release into 32 flag slots on lines never touched by RMWs.
__device__ __forceinline__ void gbar_arrive(unsigned int* sub, unsigned int* top,
                                            unsigned int* flags, unsigned int bk,
                                            int blk, int tid){
  if (tid == 0){
    const unsigned int o =
        __hip_atomic_fetch_add(sub + (unsigned)(blk >> 3) * 8u, 1u,
                               __ATOMIC_RELAXED, __HIP_MEMORY_SCOPE_AGENT);
    if (o == 8u * bk - 1u){
      const unsigned int t =
          __hip_atomic_fetch_add(top, 1u, __ATOMIC_RELAXED,
                                 __HIP_MEMORY_SCOPE_AGENT);
      if (t == 32u * bk - 1u){
        #pragma unroll
        for (int i = 0; i < 32; ++i)
          __hip_atomic_store(flags + i * 8, bk, __ATOMIC_RELAXED,
                             __HIP_MEMORY_SCOPE_AGENT);
      }
    }
  }
}
__device__ __forceinline__ void gbar_wait(unsigned int* flags, unsigned int bk,
                                          int blk, int tid){
  if (tid == 0){
    while (__hip_atomic_load(flags + (unsigned)(blk >> 3) * 8u,
                             __ATOMIC_RELAXED, __HIP_MEMORY_SCOPE_AGENT) < bk)
      __builtin_amdgcn_s_sleep(2);
  }
  __syncthreads();
}

// 8-block batch-group sync (cumulative counter, target 8*gk)
__device__ __forceinline__ void gsync(unsigned int* grp, int b,
                                      unsigned int gk, int tid){
  __syncthreads();
  if (tid == 0){
    __hip_atomic_fetch_add(grp + (unsigned)b * 8u, 1u,
                           __ATOMIC_RELAXED, __HIP_MEMORY_SCOPE_AGENT);
    while (__hip_atomic_load(grp + (unsigned)b * 8u, __ATOMIC_RELAXED,
                             __HIP_MEMORY_SCOPE_AGENT) < 8u * gk)
      __builtin_amdgcn_s_sleep(1);
  }
  __syncthreads();
}

// ---------------- fp32 -> bf16 convert ----------------
__global__ void cvtk(const float* __restrict__ src, unsigned short* __restrict__ dst, int n){
  int i = blockIdx.x * blockDim.x + threadIdx.x;
  const int stride = gridDim.x * blockDim.x;
  for (; i < n; i += stride) dst[i] = f2b(src[i]);
}

// fp32 -> (hi, lo) bf16 Dekker split
__global__ void splitk(const float* __restrict__ src, unsigned short* __restrict__ hi,
                       unsigned short* __restrict__ lo, int n){
  int i = blockIdx.x * blockDim.x + threadIdx.x;
  const int stride = gridDim.x * blockDim.x;
  for (; i < n; i += stride){
    const float x = src[i];
    const unsigned short h = f2b(x);
    hi[i] = h;
    lo[i] = f2b(x - b2f((short)h));
  }
}

// bias_g[dir][j] = bih[j] + bhh[j]
__global__ void biask(const float* bihf, const float* bhhf,
                      const float* bihb, const float* bhhb, float* bg){
  int i = blockIdx.x * blockDim.x + threadIdx.x;
  if (i < G4) bg[i] = bihf[i] + bhhf[i];
  else if (i < 2 * G4) bg[i] = bihb[i - G4] + bhhb[i - G4];
}

// out[b][t][c] = bias_c (exclusive-owner accumulates happen in the scan)
__global__ void outinit(float* out, const float* parab, const float* chapb){
  const int i = blockIdx.x * blockDim.x + threadIdx.x;
  if (i < Bz * Tz * 8){
    const int c = i & 7;
    out[i] = (c < 5) ? parab[c] : chapb[c - 5];
  }
}

// ---------------- enc_proj GEMM (split-bf16, fp32-accurate) ----------------
__global__ __launch_bounds__(256, 1) void encgemm(
    const float* __restrict__ embf,
    const unsigned short* __restrict__ wenchi, const unsigned short* __restrict__ wenclo,
    const float* __restrict__ encb, float* __restrict__ ep32)
{
  const int lane = threadIdx.x & 63, wvv = threadIdx.x >> 6;
  const int mt = blockIdx.x * 4 + wvv;
  const int m0 = mt * 16;
  const int n = lane & 15, quad = lane >> 4;
  f32x4 acc[32];
  #pragma unroll
  for (int i = 0; i < 32; ++i) acc[i] = (f32x4){0.f, 0.f, 0.f, 0.f};
  const float* ar = embf + ((size_t)(m0 + n)) * Ez;
  for (int kk = 0; kk < 24; ++kk){
    const int k = kk * 32 + quad * 8;
    const f32x4 a0 = *(const f32x4*)(ar + k);
    const f32x4 a1 = *(const f32x4*)(ar + k + 4);
    short8 ah, al;
    #pragma unroll
    for (int j = 0; j < 4; ++j){
      unsigned short h0 = f2b(a0[j]);
      ah[j] = (short)h0; al[j] = (short)f2b(a0[j] - b2f((short)h0));
      unsigned short h1 = f2b(a1[j]);
      ah[4 + j] = (short)h1; al[4 + j] = (short)f2b(a1[j] - b2f((short)h1));
    }
    #pragma unroll
    for (int nt = 0; nt < 32; ++nt){
      const size_t bo = ((size_t)(nt * 16 + n)) * Ez + k;
      const short8 bh = *(const short8*)(wenchi + bo);
      const short8 bl = *(const short8*)(wenclo + bo);
      acc[nt] = __builtin_amdgcn_mfma_f32_16x16x32_bf16(ah, bh, acc[nt], 0, 0, 0);
      acc[nt] = __builtin_amdgcn_mfma_f32_16x16x32_bf16(ah, bl, acc[nt], 0, 0, 0);
      acc[nt] = __builtin_amdgcn_mfma_f32_16x16x32_bf16(al, bh, acc[nt], 0, 0, 0);
    }
  }
  #pragma unroll
  for (int nt = 0; nt < 32; ++nt){
    const int colg = nt * 16 + n;
    const float bb = encb[colg];
    #pragma unroll
    for (int r = 0; r < 4; ++r){
      const int row = m0 + quad * 4 + r;
      ep32[(size_t)row * Hz + colg] = acc[nt][r] + bb;
    }
  }
}

// ---------------- persistent scan kernel ----------------
// LDS residency flipped vs earlier rounds: the block's emb16 slice (98 KB,
// re-read EVERY step by the ctx-partial loop — was ~25 MB/step of HBM) is
// now LDS-resident; the ep slice streams from L2/L3 (per-XCD working set
// 4 MB, coalesced, read once/step). x_t staged once per step in B (unique
// 0.2 MB/step) instead of 64x-redundant embf reads in D.
__global__ __launch_bounds__(1024) void scan_kernel(
    unsigned int* sub, unsigned int* top, unsigned int* flags, unsigned int* grp,
    unsigned short* amathi, unsigned short* amatlo,
    unsigned short* hph, unsigned short* hpl,
    float* decw, float* pctx, float* pstat,
    const float* __restrict__ biasg,
    const float* __restrict__ embf, const unsigned short* __restrict__ emb16,
    const float* __restrict__ ep32,
    const unsigned short* __restrict__ wih16, const unsigned short* __restrict__ whh16,
    const float* __restrict__ decWf, const float* __restrict__ decbias,
    const float* __restrict__ vvec,
    const float* __restrict__ paraW, const float* __restrict__ chapW,
    float* __restrict__ out)
{
  __shared__ unsigned short emb16s[64 * 768];  // 96 KB emb slice, resident all steps
  __shared__ float hs[1024];            // staged h (both dirs, this batch)
  __shared__ float red[2112];           // dec partial reduce
  __shared__ float decs[1024];          // dec for this block's batch, both dirs
  __shared__ float scs[2][64];
  __shared__ float pw[2][64];
  __shared__ float fac[2][8];
  __shared__ float gateval[512];        // 16 batches x 32 col-units

  const int blk = blockIdx.x;
  const int tid = threadIdx.x;
  const int lane = tid & 63, wv = tid >> 6;

  const int d_dir = blk >> 7, mhalf = (blk >> 6) & 1, s4d = blk & 63;  // phase-D role
  const int b_b = blk >> 3, b_q = blk & 7;        // phase-B role (batch, t-slice)
  const int t0 = b_q * 64;

  // ---- preload emb16 slice into LDS (resident for all 512 steps) ----
  {
    const unsigned int* src32 =
        (const unsigned int*)(emb16 + ((size_t)(b_b * Tz + t0)) * Ez);
    unsigned int* dst32 = (unsigned int*)emb16s;
    for (int i = tid; i < 24576; i += 1024) dst32[i] = src32[i];
  }
  // v in stride-64 lane layout (conflict-free score loop)
  float vr[8];
  #pragma unroll
  for (int j = 0; j < 8; ++j) vr[j] = vvec[j * 64 + lane];

  // ---- pin phase-D B-weight fragments in registers (same 256B every step) ----
  const int dn = lane & 15, dquad = lane >> 4;
  short8 Bfrag[4][2];
  #pragma unroll
  for (int kk = 0; kk < 4; ++kk){
    const int k = wv * 128 + kk * 32 + dquad * 8;
    #pragma unroll
    for (int j = 0; j < 2; ++j){
      const int coln = ((dn >> 2) * 512) + s4d * 8 + j * 4 + (dn & 3);
      Bfrag[kk][j] = (k < 1536)
        ? *(const short8*)(wih16 + ((size_t)(d_dir * G4) + coln) * 1536 + k)
        : *(const short8*)(whh16 + ((size_t)(d_dir * G4) + coln) * 512 + (k - 1536));
    }
  }
  // ---- pin dec_W slice: thread (j2 = tid>>4, kc = tid&15) covers row
  // (b_q*64+j2), k in {kc, kc+16, ..., kc+496} ----
  float wreg[32];
  {
    const float* wrow = decWf + ((size_t)(b_q * 64 + (tid >> 4))) * Hz + (tid & 15);
    #pragma unroll
    for (int i = 0; i < 32; ++i) wreg[i] = wrow[i * 16];
  }
  float db_r = 0.f;
  if (tid < 128) db_r = decbias[b_q * 64 + (tid & 63)];

  // ---- pin out-projection weights ----
  float wcp[8];
  {
    const int c8 = wv >> 1, half = wv & 1;
    const float* Wrow = (c8 < 5) ? (paraW + (size_t)c8 * 1024)
                                 : (chapW + (size_t)(c8 - 5) * 1024);
    #pragma unroll
    for (int i = 0; i < 8; ++i) wcp[i] = Wrow[half * 512 + i * 64 + lane];
  }

  // ---- pin pointwise constants (tid<128): 16 batches x 8 cols ----
  const int p_lb = tid >> 3, p_u = tid & 7;
  const int p_jh = s4d * 8 + p_u;
  const int p_batch = mhalf * 16 + (p_lb & 15);
  float bgi = 0.f, bgf = 0.f, bgg = 0.f, bgo = 0.f;
  float creg = 0.f;
  if (tid < 128){
    bgi = biasg[d_dir * G4 + p_jh];
    bgf = biasg[d_dir * G4 + 512 + p_jh];
    bgg = biasg[d_dir * G4 + 1024 + p_jh];
    bgo = biasg[d_dir * G4 + 1536 + p_jh];
  }

  const int abatch = mhalf * 16 + dn;   // this block's D A-row (batch)

  unsigned int bk = 0, gk = 0;

  for (int s = 0; s < NSTEP; ++s){
    const int par = s & 1;
    // ============ Phase B: dec GEMV + attention for (b_b, t-slice) ============
    {
      // stage h (hi+lo reconstruction) into LDS; x_t staging on lanes 512..607
      if (tid < 512){
        const int dir = tid >> 8, cw = tid & 255;
        const unsigned int wb = (((unsigned)par * 2 + dir) * Bz + b_b) * 256u + cw;
        const unsigned int hiw = ald32(((const unsigned int*)hph) + wb);
        const unsigned int low = ald32(((const unsigned int*)hpl) + wb);
        hs[dir * 512 + 2 * cw]     = b2f((short)(hiw & 0xffffu)) + b2f((short)(low & 0xffffu));
        hs[dir * 512 + 2 * cw + 1] = b2f((short)(hiw >> 16))     + b2f((short)(low >> 16));
      } else if (tid < 608){
        const int i2 = tid - 512;
        const int dir = i2 / 48, p = i2 % 48;
        const int e = b_q * 96 + 2 * p;
        const int ts = dir ? (Tz - 1 - s) : s;
        const float x0 = embf[((size_t)(b_b * Tz + ts)) * Ez + e];
        const float x1 = embf[((size_t)(b_b * Tz + ts)) * Ez + e + 1];
        const unsigned int u0 = pk(x0), u1 = pk(x1);
        const unsigned wi = (((unsigned)(dir * Bz + b_b)) * AK + 768u + (unsigned)e) >> 1;
        ast32(((unsigned int*)amathi) + wi, (u0 >> 16) | (u1 & 0xffff0000u));
        ast32(((unsigned int*)amatlo) + wi, (u0 & 0xffffu) | ((u1 & 0xffffu) << 16));
      }
      __syncthreads();
      // dec partials from register-pinned dec_W
      {
        const int kc = tid & 15, j2 = tid >> 4;
        float a0 = 0.f, a1 = 0.f;
        #pragma unroll
        for (int i = 0; i < 32; ++i){
          a0 += hs[kc + i * 16] * wreg[i];
          a1 += hs[512 + kc + i * 16] * wreg[i];
        }
        red[kc * 132 + j2] = a0;
        red[kc * 132 + 66 + j2] = a1;
      }
      __syncthreads();
      if (tid < 128){
        const int dir = tid >> 6, j2 = tid & 63;
        float ssum = 0.f;
        #pragma unroll
        for (int i = 0; i < 16; ++i) ssum += red[i * 132 + dir * 66 + j2];
        ast32f(decw + ((size_t)(dir * Bz + b_b)) * Hz + b_q * 64 + j2, ssum + db_r);
      }
      // ---- split group-sync #1: arrive, out-projection for h_{s-1} in the
      // wait window (exclusive owner -> plain agent RMW, zero contention) ----
      __syncthreads();
      ++gk;
      if (tid == 0)
        __hip_atomic_fetch_add(grp + (unsigned)b_b * 8u, 1u,
                               __ATOMIC_RELAXED, __HIP_MEMORY_SCOPE_AGENT);
      if (s > 0 && b_q == (s & 7)){
        const int half = wv & 1, c8 = wv >> 1;
        float vv = 0.f;
        #pragma unroll
        for (int i = 0; i < 8; ++i)
          vv += hs[half * 512 + i * 64 + lane] * wcp[i];
        vv = wsum(vv);
        if (lane == 0){
          const int ts = half ? (Tz - s) : (s - 1);
          float* po = out + ((size_t)(b_b * Tz + ts)) * 8 + c8;
          ast32f(po, ald32f(po) + vv);
        }
      }
      if (tid == 0){
        while (__hip_atomic_load(grp + (unsigned)b_b * 8u, __ATOMIC_RELAXED,
                                 __HIP_MEMORY_SCOPE_AGENT) < 8u * gk)
          __builtin_amdgcn_s_sleep(1);
      }
      __syncthreads();

      // stage full dec (both dirs) into LDS
      decs[tid] = ald32f(decw + (((size_t)(tid >> 9)) * Bz + b_b) * Hz + (tid & 511));
      __syncthreads();
      float dff[8], dfb[8];
      #pragma unroll
      for (int j = 0; j < 8; ++j){
        dff[j] = decs[j * 64 + lane];
        dfb[j] = decs[512 + j * 64 + lane];
      }
      // scores: ep streamed from L2/L3 (coalesced 256B segments)
      #pragma unroll 1
      for (int i = 0; i < 4; ++i){
        const int tl = wv * 4 + i;
        const float* er = ep32 + ((size_t)(b_b * Tz + t0 + tl)) * Hz;
        float ev[8];
        #pragma unroll
        for (int j = 0; j < 8; ++j) ev[j] = er[j * 64 + lane];
        float sf = 0.f, sb = 0.f;
        #pragma unroll
        for (int j = 0; j < 8; ++j){
          sf += vr[j] * fast_tanh(ev[j] + dff[j]);
          sb += vr[j] * fast_tanh(ev[j] + dfb[j]);
        }
        sf = wsum(sf); sb = wsum(sb);
        if (lane == 0){ scs[0][tl] = sf; scs[1][tl] = sb; }
      }
      __syncthreads();
      if (wv < 2){
        const float sv = scs[wv][lane];
        const float m = wmaxr(sv);
        const float p = __expf(sv - m);
        const float l = wsum(p);
        pw[wv][lane] = p;
        if (lane == 0){
          ast32f(pstat + (((wv * Bz) + b_b) * 8 + b_q) * 2 + 0, m);
          ast32f(pstat + (((wv * Bz) + b_b) * 8 + b_q) * 2 + 1, l);
        }
      }
      __syncthreads();
      // partial ctx from the LDS-resident emb16 slice (u32 = 2 bf16 cols)
      if (lane < 24){
        const int e2 = wv * 24 + lane;   // u32 col index, 0..383
        const unsigned int* s32 = (const unsigned int*)emb16s;
        float aF0 = 0.f, aF1 = 0.f, aB0 = 0.f, aB1 = 0.f;
        #pragma unroll 8
        for (int t = 0; t < 64; ++t){
          const unsigned int u = s32[t * 384 + e2];
          const float x0 = b2f((short)(u & 0xffffu));
          const float x1 = b2f((short)(u >> 16));
          const float w0 = pw[0][t], w1 = pw[1][t];
          aF0 += w0 * x0; aF1 += w0 * x1;
          aB0 += w1 * x0; aB1 += w1 * x1;
        }
        const int e = 2 * e2;
        float* p0 = pctx + ((size_t)(0 * Bz + b_b) * 8 + b_q) * Ez + e;
        float* p1 = pctx + ((size_t)(1 * Bz + b_b) * 8 + b_q) * Ez + e;
        ast32f(p0, aF0); ast32f(p0 + 1, aF1);
        ast32f(p1, aB0); ast32f(p1 + 1, aB1);
      }
      ++gk; gsync(grp, b_b, gk, tid);   // stats + partials ready

      // fac: parallel across 16 lanes (dir = lane>>3, qq = lane&7)
      if (tid < 16){
        const int dir = tid >> 3, qq = tid & 7;
        const float m = ald32f(pstat + (((dir * Bz) + b_b) * 8 + qq) * 2 + 0);
        const float l = ald32f(pstat + (((dir * Bz) + b_b) * 8 + qq) * 2 + 1);
        float M = m;
        #pragma unroll
        for (int o = 1; o < 8; o <<= 1) M = fmaxf(M, __shfl_xor(M, o, 8));
        const float term = l * __expf(m - M);
        float L = term;
        #pragma unroll
        for (int o = 1; o < 8; o <<= 1) L += __shfl_xor(L, o, 8);
        fac[dir][qq] = __expf(m - M) / L;
      }
      __syncthreads();
      // combine ctx cols [q*96, q*96+96) for both dirs (2 cols/thread)
      if (tid < 96){
        const int dir = tid / 48, p = tid % 48;
        const int e = b_q * 96 + 2 * p;
        float s0 = 0.f, s1 = 0.f;
        #pragma unroll
        for (int qq = 0; qq < 8; ++qq){
          const float fq = fac[dir][qq];
          const float* pb = pctx + ((size_t)(dir * Bz + b_b) * 8 + qq) * Ez + e;
          s0 += ald32f(pb) * fq;
          s1 += ald32f(pb + 1) * fq;
        }
        const unsigned int u0 = pk(s0), u1 = pk(s1);
        const unsigned wi = (((unsigned)(dir * Bz + b_b)) * AK + (unsigned)e) >> 1;
        ast32(((unsigned int*)amathi) + wi, (u0 >> 16) | (u1 & 0xffff0000u));
        ast32(((unsigned int*)amatlo) + wi, (u0 & 0xffffu) | ((u1 & 0xffffu) << 16));
      }
    }
    // ---- gbar#1 split: arrive, zero gateval in the wait window, wait ----
    ++bk;
    __syncthreads();
    gbar_arrive(sub, top, flags, bk, blk, tid);
    if (tid < 512) gateval[tid] = 0.f;
    gbar_wait(flags, bk, blk, tid);

    // ============ Phase D: gates via split-bf16 MFMA + pointwise LSTM ============
    {
      const int dir = d_dir;
      f32x4 C0 = {0.f, 0.f, 0.f, 0.f}, C1 = {0.f, 0.f, 0.f, 0.f};
      if (wv < 12){
        // ctx|x region from amat (sc reads; written this step by B)
        const size_t arow = ((size_t)(dir * Bz) + abatch) * AK;
        #pragma unroll
        for (int kk = 0; kk < 4; ++kk){
          const int k = wv * 128 + kk * 32 + dquad * 8;
          const short8 Ah = ald8s(amathi + arow + k);
          const short8 Al = ald8s(amatlo + arow + k);
          C0 = __builtin_amdgcn_mfma_f32_16x16x32_bf16(Ah, Bfrag[kk][0], C0, 0, 0, 0);
          C0 = __builtin_amdgcn_mfma_f32_16x16x32_bf16(Al, Bfrag[kk][0], C0, 0, 0, 0);
          C1 = __builtin_amdgcn_mfma_f32_16x16x32_bf16(Ah, Bfrag[kk][1], C1, 0, 0, 0);
          C1 = __builtin_amdgcn_mfma_f32_16x16x32_bf16(Al, Bfrag[kk][1], C1, 0, 0, 0);
        }
      } else {
        // h region from parity buffer (sc reads; written last step by D)
        const size_t hrow = (((size_t)par * 2 + dir) * Bz + abatch) * (size_t)Hz;
        #pragma unroll
        for (int kk = 0; kk < 4; ++kk){
          const int kh = (wv - 12) * 128 + kk * 32 + dquad * 8;
          const short8 Ah = ald8s(hph + hrow + kh);
          const short8 Al = ald8s(hpl + hrow + kh);
          C0 = __builtin_amdgcn_mfma_f32_16x16x32_bf16(Ah, Bfrag[kk][0], C0, 0, 0, 0);
          C0 = __builtin_amdgcn_mfma_f32_16x16x32_bf16(Al, Bfrag[kk][0], C0, 0, 0, 0);
          C1 = __builtin_amdgcn_mfma_f32_16x16x32_bf16(Ah, Bfrag[kk][1], C1, 0, 0, 0);
          C1 = __builtin_amdgcn_mfma_f32_16x16x32_bf16(Al, Bfrag[kk][1], C1, 0, 0, 0);
        }
      }
      // gateval[local_batch][32]: col-unit = (dn>>2)*8 + j*4 + (dn&3)
      #pragma unroll
      for (int r = 0; r < 4; ++r){
        const int rowb = (dquad * 4 + r) * 32 + (dn >> 2) * 8 + (dn & 3);
        unsafeAtomicAdd(&gateval[rowb],     C0[r]);
        unsafeAtomicAdd(&gateval[rowb + 4], C1[r]);
      }
      __syncthreads();
      if (tid < 128){
        const float gi = gateval[p_lb * 32 + p_u]       + bgi;
        const float gf = gateval[p_lb * 32 + 8 + p_u]   + bgf;
        const float gg = gateval[p_lb * 32 + 16 + p_u]  + bgg;
        const float go = gateval[p_lb * 32 + 24 + p_u]  + bgo;
        const float cnew = sigf(gf) * creg + sigf(gi) * fast_tanh(gg);
        const float hval = sigf(go) * fast_tanh(cnew);
        creg = cnew;
        // direct h handoff into the next-step parity buffer (hi/lo packed)
        const unsigned int u = pk(hval);
        const unsigned int up = __shfl_xor((int)u, 1, 64);
        if ((p_u & 1) == 0){
          const unsigned int hiw = (u >> 16) | (up & 0xffff0000u);
          const unsigned int low = (u & 0xffffu) | ((up & 0xffffu) << 16);
          const unsigned wi = ((((unsigned)(par ^ 1) * 2 + d_dir) * Bz + p_batch) * 256u)
                              + ((unsigned)p_jh >> 1);
          ast32(((unsigned int*)hph) + wi, hiw);
          ast32(((unsigned int*)hpl) + wi, low);
        }
      }
    }
    // ---- gbar#2 ----
    ++bk;
    __syncthreads();
    gbar_arrive(sub, top, flags, bk, blk, tid);
    gbar_wait(flags, bk, blk, tid);
  }

  // ---- epilogue: out-projection for h_511 (fwd t=511, bwd t=0) ----
  if (b_q == 0){
    if (tid < 512){
      const int dir = tid >> 8, cw = tid & 255;
      const unsigned int wb = ((unsigned)dir * Bz + b_b) * 256u + cw;  // par=0
      const unsigned int hiw = ald32(((const unsigned int*)hph) + wb);
      const unsigned int low = ald32(((const unsigned int*)hpl) + wb);
      hs[dir * 512 + 2 * cw]     = b2f((short)(hiw & 0xffffu)) + b2f((short)(low & 0xffffu));
      hs[dir * 512 + 2 * cw + 1] = b2f((short)(hiw >> 16))     + b2f((short)(low >> 16));
    }
    __syncthreads();
    const int half = wv & 1, c8 = wv >> 1;
    float vv = 0.f;
    #pragma unroll
    for (int i = 0; i < 8; ++i)
      vv += hs[half * 512 + i * 64 + lane] * wcp[i];
    vv = wsum(vv);
    if (lane == 0){
      const int ts = half ? 0 : (Tz - 1);
      float* po = out + ((size_t)(b_b * Tz + ts)) * 8 + c8;
      ast32f(po, ald32f(po) + vv);
    }
  }
}

extern "C" void kernel_launch(void* const* d_in, const int* in_sizes, int n_in,
                              void* d_out, int out_size, void* d_ws, size_t ws_size,
                              hipStream_t stream) {
  (void)in_sizes; (void)n_in; (void)out_size; (void)ws_size;
  const float* emb    = (const float*)d_in[0];
  const float* Wih_f  = (const float*)d_in[1];
  const float* Whh_f  = (const float*)d_in[2];
  const float* bih_f  = (const float*)d_in[3];
  const float* bhh_f  = (const float*)d_in[4];
  const float* Wih_b  = (const float*)d_in[5];
  const float* Whh_b  = (const float*)d_in[6];
  const float* bih_b  = (const float*)d_in[7];
  const float* bhh_b  = (const float*)d_in[8];
  const float* enc_W  = (const float*)d_in[9];
  const float* enc_b  = (const float*)d_in[10];
  const float* dec_W  = (const float*)d_in[11];
  const float* dec_b  = (const float*)d_in[12];
  const float* vvec   = (const float*)d_in[13];
  const float* paraW  = (const float*)d_in[14];
  const float* parab  = (const float*)d_in[15];
  const float* chapW  = (const float*)d_in[16];
  const float* chapb  = (const float*)d_in[17];
  float* out = (float*)d_out;

  uint8_t* w = (uint8_t*)d_ws;
  unsigned int* sub   = (unsigned int*)(w + OFF_SUB);
  unsigned int* grp   = (unsigned int*)(w + OFF_GRP);
  unsigned int* flags = (unsigned int*)(w + OFF_FLAGS);
  unsigned int* top   = (unsigned int*)(w + OFF_TOP);
  unsigned short* amathi = (unsigned short*)(w + OFF_AMATH);
  unsigned short* amatlo = (unsigned short*)(w + OFF_AMATL);
  unsigned short* hph    = (unsigned short*)(w + OFF_HPH);
  unsigned short* hpl    = (unsigned short*)(w + OFF_HPL);
  float* decw   = (float*)(w + OFF_DEC);
  float* pstat  = (float*)(w + OFF_PSTAT);
  float* biasg  = (float*)(w + OFF_BIASG);
  float* pctx   = (float*)(w + OFF_PCTX);
  unsigned short* emb16  = (unsigned short*)(w + OFF_EMB16);
  float* ep32   = (float*)(w + OFF_EP32);
  unsigned short* wih16 = (unsigned short*)(w + OFF_WIH);
  unsigned short* whh16 = (unsigned short*)(w + OFF_WHH);
  unsigned short* wenchi = (unsigned short*)(w + OFF_WENCHI);
  unsigned short* wenclo = (unsigned short*)(w + OFF_WENCLO);

  // weight converts (gate weights bf16-hi only; enc split for fp32-accurate ep)
  cvtk<<<512, 256, 0, stream>>>(Wih_f, wih16,               G4 * 2 * Ez);
  cvtk<<<512, 256, 0, stream>>>(Wih_b, wih16 + G4 * 2 * Ez, G4 * 2 * Ez);
  cvtk<<<256, 256, 0, stream>>>(Whh_f, whh16,               G4 * Hz);
  cvtk<<<256, 256, 0, stream>>>(Whh_b, whh16 + G4 * Hz,     G4 * Hz);
  splitk<<<256, 256, 0, stream>>>(enc_W, wenchi, wenclo, Hz * Ez);
  cvtk<<<1024, 256, 0, stream>>>(emb, emb16, Bz * Tz * Ez);
  biask<<<16, 256, 0, stream>>>(bih_f, bhh_f, bih_b, bhh_b, biasg);

  // enc_proj — wenchi aliases the scan-only amat..dec span and wenclo the
  // pctx head, so encgemm must run BEFORE the ctrl memset below
  encgemm<<<256, 256, 0, stream>>>(emb, wenchi, wenclo, enc_b, ep32);

  // zero control/state region (barriers, flags, group counters, amat, hp)
  hipMemsetAsync(d_ws, 0, CTRL_BYTES, stream);

  // out = bias (scan accumulates exclusive-owner contributions)
  outinit<<<512, 256, 0, stream>>>(out, parab, chapb);

  // persistent bidirectional attention-LSTM scan
  scan_kernel<<<NBLK, 1024, 0, stream>>>(
      sub, top, flags, grp, amathi, amatlo, hph, hpl, decw, pctx, pstat, biasg,
      emb, emb16, ep32, wih16, whh16,
      dec_W, dec_b, vvec, paraW, chapW, out);
}

// Round 9
// 23924.356 us; speedup vs baseline: 1.6344x; 1.0381x over previous
//
#include <hip/hip_runtime.h>
#include <stdint.h>

// Problem sizes
#define Bz 32
#define Tz 512
#define Ez 768
#define Hz 512
#define G4 2048      // 4*H
#define AK 1536      // staged A-matrix K: [ctx(768) | x_t(768)]; h in parity bufs
#define NBLK 256
#define NSTEP 512

typedef __attribute__((ext_vector_type(8))) short short8;
typedef __attribute__((ext_vector_type(4))) float f32x4;

// ---------------- ws layout (bytes) — total 77880448 <= proven 77881344 ----------------
#define OFF_SUB    0u            // 2 halves x 16 sub-counters, 32B stride = 1024
#define OFF_GRP    1024u         // 32 group counters, 32B stride = 1024
#define OFF_FLAGS  2048u         // 2 halves x 16 release-flag slots, 32B stride = 1024
#define OFF_TOP    3072u         // 2 top counters, 64B apart = 128
#define OFF_AMATH  3200u         // 64*1536 bf16 = 196608 (ctx|x)
#define OFF_AMATL  199808u       // 196608
#define OFF_HPH    396416u       // 2par*2dir*32*512 bf16 hi = 131072
#define OFF_HPL    527488u       // 131072
#define CTRL_BYTES 658560u       // memset-0 (after encgemm): sub/grp/flags/top/amat/hp
#define OFF_DEC    658560u       // 2*32*512 f32 = 131072 (write-before-read each step)
#define OFF_PSTAT  789632u       // 4096
#define OFF_BIASG  793728u       // 16384
#define OFF_PCTX   810112u       // 2*32*8*768 f32 = 1572864
#define OFF_EMB16  2382976u      // 32*512*768 bf16 = 25165824
#define OFF_EP32   27548800u     // 32*512*512 f32 = 33554432
#define OFF_WIH    61103232u     // 12582912
#define OFF_WHH    73686144u     // 4194304 -> ends 77880448
// wenc hi aliases amat..dec (786432 B exactly: 3200..789632); lo aliases pctx head.
// encgemm runs BEFORE the ctrl memset and before the scan writes these regions.
#define OFF_WENCHI OFF_AMATH
#define OFF_WENCLO OFF_PCTX
#define WS_NEEDED  77880448u

__device__ __forceinline__ float b2f(short s){
  union { unsigned int u; float f; } w;
  w.u = ((unsigned int)(unsigned short)s) << 16;
  return w.f;
}
__device__ __forceinline__ unsigned short f2b(float f){
  union { float f; unsigned int u; } w; w.f = f;
  unsigned int u = w.u;
  return (unsigned short)((u + 0x7fffu + ((u >> 16) & 1u)) >> 16);
}
__device__ __forceinline__ unsigned int pk(float x){
  const unsigned short h = f2b(x);
  const unsigned short l = f2b(x - b2f((short)h));
  return ((unsigned int)h << 16) | (unsigned int)l;
}
__device__ __forceinline__ float fast_tanh(float x){
  float e = __expf(2.f * x);
  return 1.f - 2.f / (e + 1.f);
}
__device__ __forceinline__ float sigf(float x){
  return 1.f / (1.f + __expf(-x));
}
__device__ __forceinline__ float wsum(float v){
  #pragma unroll
  for (int o = 32; o > 0; o >>= 1) v += __shfl_xor(v, o, 64);
  return v;
}
__device__ __forceinline__ float wmaxr(float v){
  #pragma unroll
  for (int o = 32; o > 0; o >>= 1) v = fmaxf(v, __shfl_xor(v, o, 64));
  return v;
}

// relaxed agent-scope atomic access (sc-flagged; bypasses non-coherent L2)
__device__ __forceinline__ unsigned int ald32(const unsigned int* p){
  return __hip_atomic_load(p, __ATOMIC_RELAXED, __HIP_MEMORY_SCOPE_AGENT);
}
__device__ __forceinline__ float ald32f(const float* p){
  return __hip_atomic_load(p, __ATOMIC_RELAXED, __HIP_MEMORY_SCOPE_AGENT);
}
__device__ __forceinline__ unsigned long long ald64(const unsigned long long* p){
  return __hip_atomic_load(p, __ATOMIC_RELAXED, __HIP_MEMORY_SCOPE_AGENT);
}
__device__ __forceinline__ void ast32(unsigned int* p, unsigned int v){
  __hip_atomic_store(p, v, __ATOMIC_RELAXED, __HIP_MEMORY_SCOPE_AGENT);
}
__device__ __forceinline__ void ast32f(float* p, float v){
  __hip_atomic_store(p, v, __ATOMIC_RELAXED, __HIP_MEMORY_SCOPE_AGENT);
}
__device__ __forceinline__ short8 ald8s(const unsigned short* p){
  union { unsigned long long u[2]; short8 s; } w;
  const unsigned long long* q = (const unsigned long long*)p;
  w.u[0] = ald64(q);
  w.u[1] = ald64(q + 1);
  return w.s;
}

// HALF-grid barrier (128 blocks), split arrive/wait. The computation
// decomposes into two independent 16-batch pipelines (a block's B-role batch
// half always equals its D-role half), so each half syncs only its own 128
// blocks: 16 sub-counters (8 blocks each) -> per-half top -> 16 flag slots
// on lines never touched by RMWs. Halves drift freely past each other.
__device__ __forceinline__ void gbar_arrive(unsigned int* sub, unsigned int* top,
                                            unsigned int* flags, unsigned int bk,
                                            int half, int local, int tid){
  if (tid == 0){
    const unsigned int o =
        __hip_atomic_fetch_add(sub + (unsigned)(half * 16 + (local >> 3)) * 8u, 1u,
                               __ATOMIC_RELAXED, __HIP_MEMORY_SCOPE_AGENT);
    if (o == 8u * bk - 1u){
      const unsigned int t =
          __hip_atomic_fetch_add(top + half * 16, 1u, __ATOMIC_RELAXED,
                                 __HIP_MEMORY_SCOPE_AGENT);
      if (t == 16u * bk - 1u){
        #pragma unroll
        for (int i = 0; i < 16; ++i)
          __hip_atomic_store(flags + (half * 16 + i) * 8, bk, __ATOMIC_RELAXED,
                             __HIP_MEMORY_SCOPE_AGENT);
      }
    }
  }
}
__device__ __forceinline__ void gbar_wait(unsigned int* flags, unsigned int bk,
                                          int half, int local, int tid){
  if (tid == 0){
    while (__hip_atomic_load(flags + (unsigned)(half * 16 + (local >> 3)) * 8u,
                             __ATOMIC_RELAXED, __HIP_MEMORY_SCOPE_AGENT) < bk)
      __builtin_amdgcn_s_sleep(2);
  }
  __syncthreads();
}

// 8-block batch-group sync (cumulative counter, target 8*gk)
__device__ __forceinline__ void gsync(unsigned int* grp, int b,
                                      unsigned int gk, int tid){
  __syncthreads();
  if (tid == 0){
    __hip_atomic_fetch_add(grp + (unsigned)b * 8u, 1u,
                           __ATOMIC_RELAXED, __HIP_MEMORY_SCOPE_AGENT);
    while (__hip_atomic_load(grp + (unsigned)b * 8u, __ATOMIC_RELAXED,
                             __HIP_MEMORY_SCOPE_AGENT) < 8u * gk)
      __builtin_amdgcn_s_sleep(1);
  }
  __syncthreads();
}

// ---------------- fp32 -> bf16 convert ----------------
__global__ void cvtk(const float* __restrict__ src, unsigned short* __restrict__ dst, int n){
  int i = blockIdx.x * blockDim.x + threadIdx.x;
  const int stride = gridDim.x * blockDim.x;
  for (; i < n; i += stride) dst[i] = f2b(src[i]);
}

// fp32 -> (hi, lo) bf16 Dekker split
__global__ void splitk(const float* __restrict__ src, unsigned short* __restrict__ hi,
                       unsigned short* __restrict__ lo, int n){
  int i = blockIdx.x * blockDim.x + threadIdx.x;
  const int stride = gridDim.x * blockDim.x;
  for (; i < n; i += stride){
    const float x = src[i];
    const unsigned short h = f2b(x);
    hi[i] = h;
    lo[i] = f2b(x - b2f((short)h));
  }
}

// bias_g[dir][j] = bih[j] + bhh[j]
__global__ void biask(const float* bihf, const float* bhhf,
                      const float* bihb, const float* bhhb, float* bg){
  int i = blockIdx.x * blockDim.x + threadIdx.x;
  if (i < G4) bg[i] = bihf[i] + bhhf[i];
  else if (i < 2 * G4) bg[i] = bihb[i - G4] + bhhb[i - G4];
}

// out[b][t][c] = bias_c (exclusive-owner accumulates happen in the scan)
__global__ void outinit(float* out, const float* parab, const float* chapb){
  const int i = blockIdx.x * blockDim.x + threadIdx.x;
  if (i < Bz * Tz * 8){
    const int c = i & 7;
    out[i] = (c < 5) ? parab[c] : chapb[c - 5];
  }
}

// ---------------- enc_proj GEMM (split-bf16, fp32-accurate) ----------------
__global__ __launch_bounds__(256, 1) void encgemm(
    const float* __restrict__ embf,
    const unsigned short* __restrict__ wenchi, const unsigned short* __restrict__ wenclo,
    const float* __restrict__ encb, float* __restrict__ ep32)
{
  const int lane = threadIdx.x & 63, wvv = threadIdx.x >> 6;
  const int mt = blockIdx.x * 4 + wvv;
  const int m0 = mt * 16;
  const int n = lane & 15, quad = lane >> 4;
  f32x4 acc[32];
  #pragma unroll
  for (int i = 0; i < 32; ++i) acc[i] = (f32x4){0.f, 0.f, 0.f, 0.f};
  const float* ar = embf + ((size_t)(m0 + n)) * Ez;
  for (int kk = 0; kk < 24; ++kk){
    const int k = kk * 32 + quad * 8;
    const f32x4 a0 = *(const f32x4*)(ar + k);
    const f32x4 a1 = *(const f32x4*)(ar + k + 4);
    short8 ah, al;
    #pragma unroll
    for (int j = 0; j < 4; ++j){
      unsigned short h0 = f2b(a0[j]);
      ah[j] = (short)h0; al[j] = (short)f2b(a0[j] - b2f((short)h0));
      unsigned short h1 = f2b(a1[j]);
      ah[4 + j] = (short)h1; al[4 + j] = (short)f2b(a1[j] - b2f((short)h1));
    }
    #pragma unroll
    for (int nt = 0; nt < 32; ++nt){
      const size_t bo = ((size_t)(nt * 16 + n)) * Ez + k;
      const short8 bh = *(const short8*)(wenchi + bo);
      const short8 bl = *(const short8*)(wenclo + bo);
      acc[nt] = __builtin_amdgcn_mfma_f32_16x16x32_bf16(ah, bh, acc[nt], 0, 0, 0);
      acc[nt] = __builtin_amdgcn_mfma_f32_16x16x32_bf16(ah, bl, acc[nt], 0, 0, 0);
      acc[nt] = __builtin_amdgcn_mfma_f32_16x16x32_bf16(al, bh, acc[nt], 0, 0, 0);
    }
  }
  #pragma unroll
  for (int nt = 0; nt < 32; ++nt){
    const int colg = nt * 16 + n;
    const float bb = encb[colg];
    #pragma unroll
    for (int r = 0; r < 4; ++r){
      const int row = m0 + quad * 4 + r;
      ep32[(size_t)row * Hz + colg] = acc[nt][r] + bb;
    }
  }
}

// ---------------- persistent scan kernel ----------------
// Two independent 16-batch half-pipelines (128 blocks each, own barriers).
// Role maps: half = blk>>7, local = blk&127.
//   B-role:  b_b = half*16 + (local&15), b_q = local>>4  -> a batch's 8
//            gsync partners differ only in bits 4-6, so blk%8 is invariant:
//            partners co-reside on one XCD (locality for gsync/pctx/decw).
//   D-role:  d_dir = local>>6, s4d = local&63, mhalf = half.
__global__ __launch_bounds__(1024) void scan_kernel(
    unsigned int* sub, unsigned int* top, unsigned int* flags, unsigned int* grp,
    unsigned short* amathi, unsigned short* amatlo,
    unsigned short* hph, unsigned short* hpl,
    float* decw, float* pctx, float* pstat,
    const float* __restrict__ biasg,
    const float* __restrict__ embf, const unsigned short* __restrict__ emb16,
    const float* __restrict__ ep32,
    const unsigned short* __restrict__ wih16, const unsigned short* __restrict__ whh16,
    const float* __restrict__ decWf, const float* __restrict__ decbias,
    const float* __restrict__ vvec,
    const float* __restrict__ paraW, const float* __restrict__ chapW,
    float* __restrict__ out)
{
  __shared__ unsigned short emb16s[64 * 768];  // 96 KB emb slice, resident all steps
  __shared__ float hs[1024];            // staged h (both dirs, this batch)
  __shared__ float red[2112];           // dec partial reduce
  __shared__ float decs[1024];          // dec for this block's batch, both dirs
  __shared__ float scs[2][64];
  __shared__ float pw[2][64];
  __shared__ float fac[2][8];
  __shared__ float gateval[512];        // 16 batches x 32 col-units

  const int blk = blockIdx.x;
  const int tid = threadIdx.x;
  const int lane = tid & 63, wv = tid >> 6;

  const int half = blk >> 7, local = blk & 127;
  const int b_b = half * 16 + (local & 15), b_q = local >> 4;  // phase-B role
  const int d_dir = local >> 6, s4d = local & 63, mhalf = half; // phase-D role
  const int t0 = b_q * 64;

  // ---- preload emb16 slice into LDS (resident for all 512 steps) ----
  {
    const unsigned int* src32 =
        (const unsigned int*)(emb16 + ((size_t)(b_b * Tz + t0)) * Ez);
    unsigned int* dst32 = (unsigned int*)emb16s;
    for (int i = tid; i < 24576; i += 1024) dst32[i] = src32[i];
  }
  // v in stride-64 lane layout (conflict-free score loop)
  float vr[8];
  #pragma unroll
  for (int j = 0; j < 8; ++j) vr[j] = vvec[j * 64 + lane];

  // ---- pin phase-D B-weight fragments in registers (same 256B every step) ----
  const int dn = lane & 15, dquad = lane >> 4;
  short8 Bfrag[4][2];
  #pragma unroll
  for (int kk = 0; kk < 4; ++kk){
    const int k = wv * 128 + kk * 32 + dquad * 8;
    #pragma unroll
    for (int j = 0; j < 2; ++j){
      const int coln = ((dn >> 2) * 512) + s4d * 8 + j * 4 + (dn & 3);
      Bfrag[kk][j] = (k < 1536)
        ? *(const short8*)(wih16 + ((size_t)(d_dir * G4) + coln) * 1536 + k)
        : *(const short8*)(whh16 + ((size_t)(d_dir * G4) + coln) * 512 + (k - 1536));
    }
  }
  // ---- pin dec_W slice: thread (j2 = tid>>4, kc = tid&15) covers row
  // (b_q*64+j2), k in {kc, kc+16, ..., kc+496} ----
  float wreg[32];
  {
    const float* wrow = decWf + ((size_t)(b_q * 64 + (tid >> 4))) * Hz + (tid & 15);
    #pragma unroll
    for (int i = 0; i < 32; ++i) wreg[i] = wrow[i * 16];
  }
  float db_r = 0.f;
  if (tid < 128) db_r = decbias[b_q * 64 + (tid & 63)];

  // ---- pin out-projection weights ----
  float wcp[8];
  {
    const int c8 = wv >> 1, whalf = wv & 1;
    const float* Wrow = (c8 < 5) ? (paraW + (size_t)c8 * 1024)
                                 : (chapW + (size_t)(c8 - 5) * 1024);
    #pragma unroll
    for (int i = 0; i < 8; ++i) wcp[i] = Wrow[whalf * 512 + i * 64 + lane];
  }

  // ---- pin pointwise constants (tid<128): 16 batches x 8 cols ----
  const int p_lb = tid >> 3, p_u = tid & 7;
  const int p_jh = s4d * 8 + p_u;
  const int p_batch = mhalf * 16 + (p_lb & 15);
  float bgi = 0.f, bgf = 0.f, bgg = 0.f, bgo = 0.f;
  float creg = 0.f;
  if (tid < 128){
    bgi = biasg[d_dir * G4 + p_jh];
    bgf = biasg[d_dir * G4 + 512 + p_jh];
    bgg = biasg[d_dir * G4 + 1024 + p_jh];
    bgo = biasg[d_dir * G4 + 1536 + p_jh];
  }

  const int abatch = mhalf * 16 + dn;   // this block's D A-row (batch)

  unsigned int bk = 0, gk = 0;

  for (int s = 0; s < NSTEP; ++s){
    const int par = s & 1;
    // ============ Phase B: dec GEMV + attention for (b_b, t-slice) ============
    {
      // stage h (hi+lo reconstruction) into LDS; x_t staging on lanes 512..607
      if (tid < 512){
        const int dir = tid >> 8, cw = tid & 255;
        const unsigned int wb = (((unsigned)par * 2 + dir) * Bz + b_b) * 256u + cw;
        const unsigned int hiw = ald32(((const unsigned int*)hph) + wb);
        const unsigned int low = ald32(((const unsigned int*)hpl) + wb);
        hs[dir * 512 + 2 * cw]     = b2f((short)(hiw & 0xffffu)) + b2f((short)(low & 0xffffu));
        hs[dir * 512 + 2 * cw + 1] = b2f((short)(hiw >> 16))     + b2f((short)(low >> 16));
      } else if (tid < 608){
        const int i2 = tid - 512;
        const int dir = i2 / 48, p = i2 % 48;
        const int e = b_q * 96 + 2 * p;
        const int ts = dir ? (Tz - 1 - s) : s;
        const float x0 = embf[((size_t)(b_b * Tz + ts)) * Ez + e];
        const float x1 = embf[((size_t)(b_b * Tz + ts)) * Ez + e + 1];
        const unsigned int u0 = pk(x0), u1 = pk(x1);
        const unsigned wi = (((unsigned)(dir * Bz + b_b)) * AK + 768u + (unsigned)e) >> 1;
        ast32(((unsigned int*)amathi) + wi, (u0 >> 16) | (u1 & 0xffff0000u));
        ast32(((unsigned int*)amatlo) + wi, (u0 & 0xffffu) | ((u1 & 0xffffu) << 16));
      }
      __syncthreads();
      // dec partials from register-pinned dec_W
      {
        const int kc = tid & 15, j2 = tid >> 4;
        float a0 = 0.f, a1 = 0.f;
        #pragma unroll
        for (int i = 0; i < 32; ++i){
          a0 += hs[kc + i * 16] * wreg[i];
          a1 += hs[512 + kc + i * 16] * wreg[i];
        }
        red[kc * 132 + j2] = a0;
        red[kc * 132 + 66 + j2] = a1;
      }
      __syncthreads();
      if (tid < 128){
        const int dir = tid >> 6, j2 = tid & 63;
        float ssum = 0.f;
        #pragma unroll
        for (int i = 0; i < 16; ++i) ssum += red[i * 132 + dir * 66 + j2];
        ast32f(decw + ((size_t)(dir * Bz + b_b)) * Hz + b_q * 64 + j2, ssum + db_r);
      }
      // ---- split group-sync #1: arrive, out-projection for h_{s-1} in the
      // wait window (exclusive owner -> plain agent RMW, zero contention) ----
      __syncthreads();
      ++gk;
      if (tid == 0)
        __hip_atomic_fetch_add(grp + (unsigned)b_b * 8u, 1u,
                               __ATOMIC_RELAXED, __HIP_MEMORY_SCOPE_AGENT);
      if (s > 0 && b_q == (s & 7)){
        const int ohalf = wv & 1, c8 = wv >> 1;
        float vv = 0.f;
        #pragma unroll
        for (int i = 0; i < 8; ++i)
          vv += hs[ohalf * 512 + i * 64 + lane] * wcp[i];
        vv = wsum(vv);
        if (lane == 0){
          const int ts = ohalf ? (Tz - s) : (s - 1);
          float* po = out + ((size_t)(b_b * Tz + ts)) * 8 + c8;
          ast32f(po, ald32f(po) + vv);
        }
      }
      if (tid == 0){
        while (__hip_atomic_load(grp + (unsigned)b_b * 8u, __ATOMIC_RELAXED,
                                 __HIP_MEMORY_SCOPE_AGENT) < 8u * gk)
          __builtin_amdgcn_s_sleep(1);
      }
      __syncthreads();

      // stage full dec (both dirs) into LDS
      decs[tid] = ald32f(decw + (((size_t)(tid >> 9)) * Bz + b_b) * Hz + (tid & 511));
      __syncthreads();
      float dff[8], dfb[8];
      #pragma unroll
      for (int j = 0; j < 8; ++j){
        dff[j] = decs[j * 64 + lane];
        dfb[j] = decs[512 + j * 64 + lane];
      }
      // scores: ep streamed from L2/L3 (coalesced 256B segments)
      #pragma unroll 1
      for (int i = 0; i < 4; ++i){
        const int tl = wv * 4 + i;
        const float* er = ep32 + ((size_t)(b_b * Tz + t0 + tl)) * Hz;
        float ev[8];
        #pragma unroll
        for (int j = 0; j < 8; ++j) ev[j] = er[j * 64 + lane];
        float sf = 0.f, sb = 0.f;
        #pragma unroll
        for (int j = 0; j < 8; ++j){
          sf += vr[j] * fast_tanh(ev[j] + dff[j]);
          sb += vr[j] * fast_tanh(ev[j] + dfb[j]);
        }
        sf = wsum(sf); sb = wsum(sb);
        if (lane == 0){ scs[0][tl] = sf; scs[1][tl] = sb; }
      }
      __syncthreads();
      if (wv < 2){
        const float sv = scs[wv][lane];
        const float m = wmaxr(sv);
        const float p = __expf(sv - m);
        const float l = wsum(p);
        pw[wv][lane] = p;
        if (lane == 0){
          ast32f(pstat + (((wv * Bz) + b_b) * 8 + b_q) * 2 + 0, m);
          ast32f(pstat + (((wv * Bz) + b_b) * 8 + b_q) * 2 + 1, l);
        }
      }
      __syncthreads();
      // partial ctx from the LDS-resident emb16 slice; dir split across
      // waves: 16 waves x 48 lanes, 1 u32 (2 bf16 cols) per thread
      if (lane < 48){
        const int cdir = wv & 1, cg = wv >> 1;
        const int e2 = cg * 48 + lane;   // u32 col index, 0..383
        const unsigned int* s32 = (const unsigned int*)emb16s;
        float a0 = 0.f, a1 = 0.f;
        #pragma unroll 8
        for (int t = 0; t < 64; ++t){
          const unsigned int u = s32[t * 384 + e2];
          const float w = pw[cdir][t];
          a0 += w * b2f((short)(u & 0xffffu));
          a1 += w * b2f((short)(u >> 16));
        }
        float* p0 = pctx + ((size_t)(cdir * Bz + b_b) * 8 + b_q) * Ez + 2 * e2;
        ast32f(p0, a0); ast32f(p0 + 1, a1);
      }
      ++gk; gsync(grp, b_b, gk, tid);   // stats + partials ready

      // fac: parallel across 16 lanes (dir = lane>>3, qq = lane&7)
      if (tid < 16){
        const int dir = tid >> 3, qq = tid & 7;
        const float m = ald32f(pstat + (((dir * Bz) + b_b) * 8 + qq) * 2 + 0);
        const float l = ald32f(pstat + (((dir * Bz) + b_b) * 8 + qq) * 2 + 1);
        float M = m;
        #pragma unroll
        for (int o = 1; o < 8; o <<= 1) M = fmaxf(M, __shfl_xor(M, o, 8));
        const float term = l * __expf(m - M);
        float L = term;
        #pragma unroll
        for (int o = 1; o < 8; o <<= 1) L += __shfl_xor(L, o, 8);
        fac[dir][qq] = __expf(m - M) / L;
      }
      __syncthreads();
      // combine ctx cols [q*96, q*96+96) for both dirs (2 cols/thread)
      if (tid < 96){
        const int dir = tid / 48, p = tid % 48;
        const int e = b_q * 96 + 2 * p;
        float s0 = 0.f, s1 = 0.f;
        #pragma unroll
        for (int qq = 0; qq < 8; ++qq){
          const float fq = fac[dir][qq];
          const float* pb = pctx + ((size_t)(dir * Bz + b_b) * 8 + qq) * Ez + e;
          s0 += ald32f(pb) * fq;
          s1 += ald32f(pb + 1) * fq;
        }
        const unsigned int u0 = pk(s0), u1 = pk(s1);
        const unsigned wi = (((unsigned)(dir * Bz + b_b)) * AK + (unsigned)e) >> 1;
        ast32(((unsigned int*)amathi) + wi, (u0 >> 16) | (u1 & 0xffff0000u));
        ast32(((unsigned int*)amatlo) + wi, (u0 & 0xffffu) | ((u1 & 0xffffu) << 16));
      }
    }
    // ---- half-barrier #1 split: arrive, zero gateval in the window, wait ----
    ++bk;
    __syncthreads();
    gbar_arrive(sub, top, flags, bk, half, local, tid);
    if (tid < 512) gateval[tid] = 0.f;
    gbar_wait(flags, bk, half, local, tid);

    // ============ Phase D: gates via split-bf16 MFMA + pointwise LSTM ============
    {
      const int dir = d_dir;
      f32x4 C0 = {0.f, 0.f, 0.f, 0.f}, C1 = {0.f, 0.f, 0.f, 0.f};
      if (wv < 12){
        // ctx|x region from amat (sc reads; written this step by B)
        const size_t arow = ((size_t)(dir * Bz) + abatch) * AK;
        #pragma unroll
        for (int kk = 0; kk < 4; ++kk){
          const int k = wv * 128 + kk * 32 + dquad * 8;
          const short8 Ah = ald8s(amathi + arow + k);
          const short8 Al = ald8s(amatlo + arow + k);
          C0 = __builtin_amdgcn_mfma_f32_16x16x32_bf16(Ah, Bfrag[kk][0], C0, 0, 0, 0);
          C0 = __builtin_amdgcn_mfma_f32_16x16x32_bf16(Al, Bfrag[kk][0], C0, 0, 0, 0);
          C1 = __builtin_amdgcn_mfma_f32_16x16x32_bf16(Ah, Bfrag[kk][1], C1, 0, 0, 0);
          C1 = __builtin_amdgcn_mfma_f32_16x16x32_bf16(Al, Bfrag[kk][1], C1, 0, 0, 0);
        }
      } else {
        // h region from parity buffer (sc reads; written last step by D)
        const size_t hrow = (((size_t)par * 2 + dir) * Bz + abatch) * (size_t)Hz;
        #pragma unroll
        for (int kk = 0; kk < 4; ++kk){
          const int kh = (wv - 12) * 128 + kk * 32 + dquad * 8;
          const short8 Ah = ald8s(hph + hrow + kh);
          const short8 Al = ald8s(hpl + hrow + kh);
          C0 = __builtin_amdgcn_mfma_f32_16x16x32_bf16(Ah, Bfrag[kk][0], C0, 0, 0, 0);
          C0 = __builtin_amdgcn_mfma_f32_16x16x32_bf16(Al, Bfrag[kk][0], C0, 0, 0, 0);
          C1 = __builtin_amdgcn_mfma_f32_16x16x32_bf16(Ah, Bfrag[kk][1], C1, 0, 0, 0);
          C1 = __builtin_amdgcn_mfma_f32_16x16x32_bf16(Al, Bfrag[kk][1], C1, 0, 0, 0);
        }
      }
      // gateval[local_batch][32]: col-unit = (dn>>2)*8 + j*4 + (dn&3)
      #pragma unroll
      for (int r = 0; r < 4; ++r){
        const int rowb = (dquad * 4 + r) * 32 + (dn >> 2) * 8 + (dn & 3);
        unsafeAtomicAdd(&gateval[rowb],     C0[r]);
        unsafeAtomicAdd(&gateval[rowb + 4], C1[r]);
      }
      __syncthreads();
      if (tid < 128){
        const float gi = gateval[p_lb * 32 + p_u]       + bgi;
        const float gf = gateval[p_lb * 32 + 8 + p_u]   + bgf;
        const float gg = gateval[p_lb * 32 + 16 + p_u]  + bgg;
        const float go = gateval[p_lb * 32 + 24 + p_u]  + bgo;
        const float cnew = sigf(gf) * creg + sigf(gi) * fast_tanh(gg);
        const float hval = sigf(go) * fast_tanh(cnew);
        creg = cnew;
        // direct h handoff into the next-step parity buffer (hi/lo packed)
        const unsigned int u = pk(hval);
        const unsigned int up = __shfl_xor((int)u, 1, 64);
        if ((p_u & 1) == 0){
          const unsigned int hiw = (u >> 16) | (up & 0xffff0000u);
          const unsigned int low = (u & 0xffffu) | ((up & 0xffffu) << 16);
          const unsigned wi = ((((unsigned)(par ^ 1) * 2 + d_dir) * Bz + p_batch) * 256u)
                              + ((unsigned)p_jh >> 1);
          ast32(((unsigned int*)hph) + wi, hiw);
          ast32(((unsigned int*)hpl) + wi, low);
        }
      }
    }
    // ---- half-barrier #2 ----
    ++bk;
    __syncthreads();
    gbar_arrive(sub, top, flags, bk, half, local, tid);
    gbar_wait(flags, bk, half, local, tid);
  }

  // ---- epilogue: out-projection for h_511 (fwd t=511, bwd t=0) ----
  if (b_q == 0){
    if (tid < 512){
      const int dir = tid >> 8, cw = tid & 255;
      const unsigned int wb = ((unsigned)dir * Bz + b_b) * 256u + cw;  // par=0
      const unsigned int hiw = ald32(((const unsigned int*)hph) + wb);
      const unsigned int low = ald32(((const unsigned int*)hpl) + wb);
      hs[dir * 512 + 2 * cw]     = b2f((short)(hiw & 0xffffu)) + b2f((short)(low & 0xffffu));
      hs[dir * 512 + 2 * cw + 1] = b2f((short)(hiw >> 16))     + b2f((short)(low >> 16));
    }
    __syncthreads();
    const int ohalf = wv & 1, c8 = wv >> 1;
    float vv = 0.f;
    #pragma unroll
    for (int i = 0; i < 8; ++i)
      vv += hs[ohalf * 512 + i * 64 + lane] * wcp[i];
    vv = wsum(vv);
    if (lane == 0){
      const int ts = ohalf ? 0 : (Tz - 1);
      float* po = out + ((size_t)(b_b * Tz + ts)) * 8 + c8;
      ast32f(po, ald32f(po) + vv);
    }
  }
}

extern "C" void kernel_launch(void* const* d_in, const int* in_sizes, int n_in,
                              void* d_out, int out_size, void* d_ws, size_t ws_size,
                              hipStream_t stream) {
  (void)in_sizes; (void)n_in; (void)out_size; (void)ws_size;
  const float* emb    = (const float*)d_in[0];
  const float* Wih_f  = (const float*)d_in[1];
  const float* Whh_f  = (const float*)d_in[2];
  const float* bih_f  = (const float*)d_in[3];
  const float* bhh_f  = (const float*)d_in[4];
  const float* Wih_b  = (const float*)d_in[5];
  const float* Whh_b  = (const float*)d_in[6];
  const float* bih_b  = (const float*)d_in[7];
  const float* bhh_b  = (const float*)d_in[8];
  const float* enc_W  = (const float*)d_in[9];
  const float* enc_b  = (const float*)d_in[10];
  const float* dec_W  = (const float*)d_in[11];
  const float* dec_b  = (const float*)d_in[12];
  const float* vvec   = (const float*)d_in[13];
  const float* paraW  = (const float*)d_in[14];
  const float* parab  = (const float*)d_in[15];
  const float* chapW  = (const float*)d_in[16];
  const float* chapb  = (const float*)d_in[17];
  float* out = (float*)d_out;

  uint8_t* w = (uint8_t*)d_ws;
  unsigned int* sub   = (unsigned int*)(w + OFF_SUB);
  unsigned int* grp   = (unsigned int*)(w + OFF_GRP);
  unsigned int* flags = (unsigned int*)(w + OFF_FLAGS);
  unsigned int* top   = (unsigned int*)(w + OFF_TOP);
  unsigned short* amathi = (unsigned short*)(w + OFF_AMATH);
  unsigned short* amatlo = (unsigned short*)(w + OFF_AMATL);
  unsigned short* hph    = (unsigned short*)(w + OFF_HPH);
  unsigned short* hpl    = (unsigned short*)(w + OFF_HPL);
  float* decw   = (float*)(w + OFF_DEC);
  float* pstat  = (float*)(w + OFF_PSTAT);
  float* biasg  = (float*)(w + OFF_BIASG);
  float* pctx   = (float*)(w + OFF_PCTX);
  unsigned short* emb16  = (unsigned short*)(w + OFF_EMB16);
  float* ep32   = (float*)(w + OFF_EP32);
  unsigned short* wih16 = (unsigned short*)(w + OFF_WIH);
  unsigned short* whh16 = (unsigned short*)(w + OFF_WHH);
  unsigned short* wenchi = (unsigned short*)(w + OFF_WENCHI);
  unsigned short* wenclo = (unsigned short*)(w + OFF_WENCLO);

  // weight converts (gate weights bf16-hi only; enc split for fp32-accurate ep)
  cvtk<<<512, 256, 0, stream>>>(Wih_f, wih16,               G4 * 2 * Ez);
  cvtk<<<512, 256, 0, stream>>>(Wih_b, wih16 + G4 * 2 * Ez, G4 * 2 * Ez);
  cvtk<<<256, 256, 0, stream>>>(Whh_f, whh16,               G4 * Hz);
  cvtk<<<256, 256, 0, stream>>>(Whh_b, whh16 + G4 * Hz,     G4 * Hz);
  splitk<<<256, 256, 0, stream>>>(enc_W, wenchi, wenclo, Hz * Ez);
  cvtk<<<1024, 256, 0, stream>>>(emb, emb16, Bz * Tz * Ez);
  biask<<<16, 256, 0, stream>>>(bih_f, bhh_f, bih_b, bhh_b, biasg);

  // enc_proj — wenchi aliases the scan-only amat..dec span and wenclo the
  // pctx head, so encgemm must run BEFORE the ctrl memset below
  encgemm<<<256, 256, 0, stream>>>(emb, wenchi, wenclo, enc_b, ep32);

  // zero control/state region (barriers, flags, group counters, amat, hp)
  hipMemsetAsync(d_ws, 0, CTRL_BYTES, stream);

  // out = bias (scan accumulates exclusive-owner contributions)
  outinit<<<512, 256, 0, stream>>>(out, parab, chapb);

  // persistent bidirectional attention-LSTM scan (two half-pipelines)
  scan_kernel<<<NBLK, 1024, 0, stream>>>(
      sub, top, flags, grp, amathi, amatlo, hph, hpl, decw, pctx, pstat, biasg,
      emb, emb16, ep32, wih16, whh16,
      dec_W, dec_b, vvec, paraW, chapW, out);
}